// Round 6
// baseline (613.933 us; speedup 1.0000x reference)
//
#include <hip/hip_runtime.h>
#include <stdint.h>

typedef unsigned short u16;
typedef unsigned int u32;
typedef _Float16 f16;
typedef _Float16 f16x8 __attribute__((ext_vector_type(8)));
typedef _Float16 f16x4 __attribute__((ext_vector_type(4)));
typedef float f32x4 __attribute__((ext_vector_type(4)));

#define B_ 32
#define C_ 256
#define S_ 1024

// ---------------------------------------------------------------------------
// Router MLP: path_prob = sigmoid(relu((g/1024) W1^T + b1) W2^T + b2)
// ---------------------------------------------------------------------------
__global__ __launch_bounds__(256) void k_mlp(
    const float* __restrict__ g,
    const float* __restrict__ w1, const float* __restrict__ b1,
    const float* __restrict__ w2, const float* __restrict__ b2,
    float* __restrict__ out)
{
    int b = blockIdx.x, tid = threadIdx.x;
    __shared__ float sg[512];
    __shared__ float sh[128];
    sg[tid]     = g[b*512 + tid]       * (1.0f/1024.0f);
    sg[tid+256] = g[b*512 + 256 + tid] * (1.0f/1024.0f);
    __syncthreads();
    if (tid < 128){
        float a = b1[tid];
        const float* w = w1 + (size_t)tid*512;
        #pragma unroll 4
        for (int k = 0; k < 512; k += 4){
            float4 wv = *(const float4*)(w + k);
            a += sg[k]*wv.x + sg[k+1]*wv.y + sg[k+2]*wv.z + sg[k+3]*wv.w;
        }
        sh[tid] = fmaxf(a, 0.f);
    }
    __syncthreads();
    if (tid < 4){
        float a = b2[tid];
        const float* w = w2 + (size_t)tid*128;
        for (int k = 0; k < 128; ++k) a += sh[k]*w[k];
        out[(size_t)8388608 + b*4 + tid] = 1.f/(1.f+expf(-a));
    }
}

// ---------------------------------------------------------------------------
// Weight convert fp32 -> f16 (Wq, Wk, Wv 256x256 ; cw 256x512)
// ---------------------------------------------------------------------------
__global__ __launch_bounds__(256) void k_cvtw(
    const float* __restrict__ Wq, const float* __restrict__ Wk,
    const float* __restrict__ Wv, const float* __restrict__ cw,
    f16* __restrict__ Wqf, f16* __restrict__ Wkf,
    f16* __restrict__ Wvf, f16* __restrict__ cwf)
{
    int i = (blockIdx.x*256 + threadIdx.x) * 4;
    const float* src; f16* dst; int off;
    if (i < 65536){ src = Wq; dst = Wqf; off = i; }
    else if (i < 131072){ src = Wk; dst = Wkf; off = i - 65536; }
    else if (i < 196608){ src = Wv; dst = Wvf; off = i - 131072; }
    else { src = cw; dst = cwf; off = i - 196608; }
    float4 v = *(const float4*)(src + off);
    f16x4 r = { (f16)v.x, (f16)v.y, (f16)v.z, (f16)v.w };
    *(f16x4*)(dst + off) = r;
}

// ---------------------------------------------------------------------------
// Input convert+transpose fp32 [c][s] -> f16 [s][c]  + fused channel-mean pool
// ---------------------------------------------------------------------------
__global__ __launch_bounds__(256) void k_cvt(
    const float* __restrict__ lidar, const float* __restrict__ hsi,
    f16* __restrict__ lidT, f16* __restrict__ hsiT,
    float* __restrict__ g)
{
    int z = blockIdx.z, which = z >> 5, b = z & 31;
    const float* src = (which ? hsi : lidar) + (size_t)b*C_*S_;
    f16* dst = (which ? hsiT : lidT) + (size_t)b*S_*C_;
    int tid = threadIdx.x;
    int c4 = blockIdx.y*64 + (tid&15)*4;
    int s4 = blockIdx.x*64 + (tid>>4)*4;
    float4 m[4];
    #pragma unroll
    for (int r = 0; r < 4; ++r) m[r] = *(const float4*)(src + (size_t)(c4+r)*S_ + s4);
    f16x4 t0 = { (f16)m[0].x, (f16)m[1].x, (f16)m[2].x, (f16)m[3].x };
    f16x4 t1 = { (f16)m[0].y, (f16)m[1].y, (f16)m[2].y, (f16)m[3].y };
    f16x4 t2 = { (f16)m[0].z, (f16)m[1].z, (f16)m[2].z, (f16)m[3].z };
    f16x4 t3 = { (f16)m[0].w, (f16)m[1].w, (f16)m[2].w, (f16)m[3].w };
    *(f16x4*)(dst + (size_t)(s4+0)*C_ + c4) = t0;
    *(f16x4*)(dst + (size_t)(s4+1)*C_ + c4) = t1;
    *(f16x4*)(dst + (size_t)(s4+2)*C_ + c4) = t2;
    *(f16x4*)(dst + (size_t)(s4+3)*C_ + c4) = t3;
    // fused pool
    float ps[4];
    #pragma unroll
    for (int r = 0; r < 4; ++r){
        ps[r] = m[r].x + m[r].y + m[r].z + m[r].w;
        ps[r] += __shfl_xor(ps[r], 16, 64);
        ps[r] += __shfl_xor(ps[r], 32, 64);   // wave sum over its 16 s
    }
    __shared__ float sred[4][64];
    int wv = tid>>6, lane = tid&63;
    if ((lane>>4) == 0){
        #pragma unroll
        for (int r = 0; r < 4; ++r) sred[wv][(lane&15)*4 + r] = ps[r];
    }
    __syncthreads();
    if (tid < 64){
        float v = sred[0][tid] + sred[1][tid] + sred[2][tid] + sred[3][tid];
        atomicAdd(&g[b*512 + which*256 + blockIdx.y*64 + tid], v);
    }
}

// ---------------------------------------------------------------------------
// QKV projections, f16 MFMA (round-2 proven form).
// combo: 0=Q_l 1=K_l 2=V_l 3=Q_h 4=K_h 5=V_h
// ---------------------------------------------------------------------------
__global__ __launch_bounds__(256) void k_qkv(
    const f16* __restrict__ lidT, const f16* __restrict__ hsiT,
    const f16* __restrict__ Wqf, const f16* __restrict__ Wkf, const f16* __restrict__ Wvf,
    const float* __restrict__ bq, const float* __restrict__ bk, const float* __restrict__ bv,
    f16* __restrict__ Qf_l, f16* __restrict__ Kf_l,
    f16* __restrict__ Qf_h, f16* __restrict__ Kf_h,
    f16* __restrict__ Qt_l, f16* __restrict__ Qt_h,
    f16* __restrict__ Vt_l, f16* __restrict__ Vt_h)
{
    int z = blockIdx.z, combo = z >> 5, b = z & 31, ww = combo % 3;
    const f16* In = ((combo < 3) ? lidT : hsiT) + (size_t)b*S_*C_;
    const f16* Wf = (ww==0) ? Wqf : (ww==1) ? Wkf : Wvf;
    const float* bias = (ww==0) ? bq : (ww==1) ? bk : bv;
    int s0 = blockIdx.x*64, o0 = blockIdx.y*64;
    int tid = threadIdx.x, w = tid>>6, lane = tid&63, quad = lane>>4, l15 = lane&15;

    __shared__ __align__(16) f16 sA[64*72];
    __shared__ __align__(16) f16 sB[64*72];

    f32x4 D[4];
    #pragma unroll
    for (int i = 0; i < 4; ++i) D[i] = (f32x4){0.f,0.f,0.f,0.f};

    int row = tid>>2, c16 = (tid&3)*16;
    for (int c0 = 0; c0 < 256; c0 += 64){
        __syncthreads();
        *(f16x8*)&sA[row*72 + c16]     = *(const f16x8*)(In + (size_t)(s0+row)*C_ + c0 + c16);
        *(f16x8*)&sA[row*72 + c16 + 8] = *(const f16x8*)(In + (size_t)(s0+row)*C_ + c0 + c16 + 8);
        *(f16x8*)&sB[row*72 + c16]     = *(const f16x8*)(Wf + (size_t)(o0+row)*C_ + c0 + c16);
        *(f16x8*)&sB[row*72 + c16 + 8] = *(const f16x8*)(Wf + (size_t)(o0+row)*C_ + c0 + c16 + 8);
        __syncthreads();
        #pragma unroll
        for (int sub = 0; sub < 2; ++sub){
            f16x8 a = *(const f16x8*)&sA[(w*16+l15)*72 + sub*32 + quad*8];
            #pragma unroll
            for (int bt = 0; bt < 4; ++bt){
                f16x8 bb = *(const f16x8*)&sB[(bt*16+l15)*72 + sub*32 + quad*8];
                D[bt] = __builtin_amdgcn_mfma_f32_16x16x32_f16(a, bb, D[bt], 0,0,0);
            }
        }
    }
    float bi[4];
    #pragma unroll
    for (int bt = 0; bt < 4; ++bt) bi[bt] = bias[o0 + bt*16 + l15];

    if (ww == 0){
        f16* F = ((combo==0) ? Qf_l : Qf_h) + (size_t)b*S_*C_;
        #pragma unroll
        for (int bt = 0; bt < 4; ++bt)
            #pragma unroll
            for (int r = 0; r < 4; ++r)
                F[(size_t)(s0 + w*16 + quad*4 + r)*C_ + o0 + bt*16 + l15] = (f16)(D[bt][r] + bi[bt]);
    } else if (ww == 1){
        f16* F = ((combo==1) ? Kf_l : Kf_h) + (size_t)b*S_*C_;
        #pragma unroll
        for (int bt = 0; bt < 4; ++bt)
            #pragma unroll
            for (int r = 0; r < 4; ++r)
                F[(size_t)(s0 + w*16 + quad*4 + r)*C_ + o0 + bt*16 + l15] = (f16)(D[bt][r] + bi[bt]);
    }
    if (ww != 1){
        __syncthreads();
        #pragma unroll
        for (int bt = 0; bt < 4; ++bt)
            #pragma unroll
            for (int r = 0; r < 4; ++r)
                sA[(bt*16+l15)*72 + w*16 + quad*4 + r] = (f16)(D[bt][r] + bi[bt]);
        __syncthreads();
        f16* T = (combo==0) ? Qt_l : (combo==3) ? Qt_h : (combo==2) ? Vt_l : Vt_h;
        T += (size_t)b*C_*S_;
        int o_r = tid>>2, s16b = (tid&3)*16;
        *(f16x8*)(T + (size_t)(o0+o_r)*S_ + s0 + s16b)     = *(const f16x8*)&sA[o_r*72 + s16b];
        *(f16x8*)(T + (size_t)(o0+o_r)*S_ + s0 + s16b + 8) = *(const f16x8*)&sA[o_r*72 + s16b + 8];
    }
}

// ---------------------------------------------------------------------------
// MFMA flash attention, v7 = round-2 schedule (proven 152.8us) + k_qv fused
// into staging: instead of prefetching precomputed QVT, prefetch Qt AND Vt
// (same [c][s] layout, same offsets) and multiply at ds_write time
// (4 v_pk_mul_f16 per f16x8, hidden in staging phase). Schedule unchanged:
// combined K+V staging, 2 barriers/tile, T14 prefetch, deferred rescale
// (THR=8), deferred l-sum, setprio. Removes the standalone k_qv kernel
// (96 MB pure-BW traffic + launch).
// VGPR: +32 over round-2 (~160 nominal) — watch FETCH for spill signature.
// ---------------------------------------------------------------------------
__global__ __launch_bounds__(256, 2) void k_attn(
    const f16* __restrict__ Qf_l, const f16* __restrict__ Kf_l,
    const f16* __restrict__ Qf_h, const f16* __restrict__ Kf_h,
    const f16* __restrict__ Qt_l, const f16* __restrict__ Qt_h,
    const f16* __restrict__ Vt_l, const f16* __restrict__ Vt_h,
    f16* __restrict__ cat)
{
    int inst = blockIdx.y;
    int b = inst >> 1, which = inst & 1;
    const f16* Qf  = (which ? Qf_h : Qf_l) + (size_t)b*S_*C_;
    const f16* Kf  = (which ? Kf_h : Kf_l) + (size_t)b*S_*C_;
    const f16* Qt  = (which ? Qt_h : Qt_l) + (size_t)b*C_*S_;  // value = Qt * other side's Vt
    const f16* Vt  = (which ? Vt_l : Vt_h) + (size_t)b*C_*S_;
    f16* outp = cat + (size_t)b*S_*512 + (which ? 0 : 256);
    int s0 = blockIdx.x*64;
    int tid = threadIdx.x, w = tid>>6, lane = tid&63, quad = lane>>4, l15 = lane&15;

    __shared__ __align__(16) f16 sK[64*264];    // [t][c] stride 264  (33792 B)
    __shared__ __align__(16) f16 sV[256*72];    // V_eff [c][t64] stride 72 (36864 B)
    __shared__ __align__(16) f16 sPw[4][16*66]; // per-wave P scratch (8448 B)

    // Q A-frags in registers: wave w owns q-rows s0+16w .. s0+16w+15
    f16x8 qa[8];
    {
        const f16* qrow = Qf + (size_t)(s0 + w*16 + l15)*C_ + quad*8;
        #pragma unroll
        for (int i = 0; i < 8; ++i) qa[i] = *(const f16x8*)(qrow + i*32);
    }
    float mrun[4], lpart[4];
    #pragma unroll
    for (int r = 0; r < 4; ++r){ mrun[r] = -1e30f; lpart[r] = 0.f; }
    f32x4 pacc[16];
    #pragma unroll
    for (int i = 0; i < 16; ++i) pacc[i] = (f32x4){0.f,0.f,0.f,0.f};

    // T14 prefetch: K rows + Qt/Vt rows (multiply happens at ds_write)
    f16x8 kreg[8], qreg[8], vreg[8];
    #pragma unroll
    for (int p = 0; p < 8; ++p){
        int idx = p*256 + tid;
        size_t voff = (size_t)(idx>>3)*S_ + (idx&7)*8;
        kreg[p] = *(const f16x8*)(Kf + (size_t)(idx>>5)*C_ + (idx&31)*8);
        qreg[p] = *(const f16x8*)(Qt + voff);
        vreg[p] = *(const f16x8*)(Vt + voff);
    }

    for (int tt = 0; tt < 16; ++tt){
        __syncthreads();                  // prev tile's MFMA reads of sK/sV done
        #pragma unroll
        for (int p = 0; p < 8; ++p){      // write staged regs; V_eff = Qt*Vt
            int idx = p*256 + tid;
            *(f16x8*)&sK[(idx>>5)*264 + (idx&31)*8] = kreg[p];
            *(f16x8*)&sV[(idx>>3)*72  + (idx&7)*8]  = qreg[p]*vreg[p];
        }
        __syncthreads();

        // issue next tile's loads NOW; they complete under QK^T/softmax/PV
        if (tt < 15){
            int t0n = (tt+1)*64;
            #pragma unroll
            for (int p = 0; p < 8; ++p){
                int idx = p*256 + tid;
                size_t voff = (size_t)(idx>>3)*S_ + t0n + (idx&7)*8;
                kreg[p] = *(const f16x8*)(Kf + (size_t)(t0n + (idx>>5))*C_ + (idx&31)*8);
                qreg[p] = *(const f16x8*)(Qt + voff);
                vreg[p] = *(const f16x8*)(Vt + voff);
            }
        }

        // ---- scores: D[16 s][64 t] per wave ----
        f32x4 sacc[4];
        #pragma unroll
        for (int bt = 0; bt < 4; ++bt) sacc[bt] = (f32x4){0.f,0.f,0.f,0.f};
        __builtin_amdgcn_s_setprio(1);
        #pragma unroll
        for (int ks = 0; ks < 8; ++ks){
            #pragma unroll
            for (int bt = 0; bt < 4; ++bt){
                f16x8 kb = *(const f16x8*)&sK[(bt*16+l15)*264 + ks*32 + quad*8];
                sacc[bt] = __builtin_amdgcn_mfma_f32_16x16x32_f16(qa[ks], kb, sacc[bt], 0,0,0);
            }
        }
        __builtin_amdgcn_s_setprio(0);

        // ---- wave-local online softmax, deferred rescale + deferred l-sum ----
        float tm[4];
        #pragma unroll
        for (int r = 0; r < 4; ++r){
            float t = fmaxf(fmaxf(sacc[0][r], sacc[1][r]), fmaxf(sacc[2][r], sacc[3][r]));
            #pragma unroll
            for (int off = 1; off < 16; off <<= 1) t = fmaxf(t, __shfl_xor(t, off, 64));
            tm[r] = t;
        }
        bool need = (tm[0] > mrun[0]+8.f) | (tm[1] > mrun[1]+8.f) |
                    (tm[2] > mrun[2]+8.f) | (tm[3] > mrun[3]+8.f);
        if (__any(need)){
            #pragma unroll
            for (int r = 0; r < 4; ++r){
                float mn = fmaxf(mrun[r], tm[r]);
                float al = __expf(mrun[r] - mn);
                mrun[r] = mn;
                lpart[r] *= al;
                #pragma unroll
                for (int cf = 0; cf < 16; ++cf) pacc[cf][r] *= al;
            }
        }
        #pragma unroll
        for (int r = 0; r < 4; ++r){
            float local = 0.f;
            #pragma unroll
            for (int bt = 0; bt < 4; ++bt){
                float p = __expf(sacc[bt][r] - mrun[r]);
                sPw[w][(quad*4+r)*66 + bt*16 + l15] = (f16)p;
                local += p;
            }
            lpart[r] += local;
        }
        // P A-frags (wave-internal LDS round-trip; no barrier)
        f16x8 pa0 = *(const f16x8*)&sPw[w][l15*66 + quad*8];
        f16x8 pa1 = *(const f16x8*)&sPw[w][l15*66 + 32 + quad*8];

        // ---- PV: D[16 s][256 c] per wave ----
        __builtin_amdgcn_s_setprio(1);
        #pragma unroll
        for (int cf = 0; cf < 16; ++cf){
            f16x8 vb0 = *(const f16x8*)&sV[(cf*16+l15)*72 + quad*8];
            f16x8 vb1 = *(const f16x8*)&sV[(cf*16+l15)*72 + 32 + quad*8];
            pacc[cf] = __builtin_amdgcn_mfma_f32_16x16x32_f16(pa0, vb0, pacc[cf], 0,0,0);
            pacc[cf] = __builtin_amdgcn_mfma_f32_16x16x32_f16(pa1, vb1, pacc[cf], 0,0,0);
        }
        __builtin_amdgcn_s_setprio(0);
    }

    // ---- epilogue: deferred l reduction + normalize ----
    #pragma unroll
    for (int r = 0; r < 4; ++r){
        #pragma unroll
        for (int off = 1; off < 16; off <<= 1) lpart[r] += __shfl_xor(lpart[r], off, 64);
    }
    #pragma unroll
    for (int r = 0; r < 4; ++r){
        int s = w*16 + quad*4 + r;
        float rl = 1.f / lpart[r];
        #pragma unroll
        for (int cf = 0; cf < 16; ++cf)
            outp[(size_t)(s0+s)*512 + cf*16 + l15] = (f16)(pacc[cf][r] * rl);
    }
}

// ---------------------------------------------------------------------------
// 1x1 conv + bias + residual, f16 MFMA (round-2 proven form)
// ---------------------------------------------------------------------------
__global__ __launch_bounds__(256) void k_conv(
    const f16* __restrict__ cat, const f16* __restrict__ cwf,
    const float* __restrict__ cb, const float* __restrict__ x,
    float* __restrict__ out)
{
    int b = blockIdx.z;
    int s0 = blockIdx.x*64, o0 = blockIdx.y*64;
    int tid = threadIdx.x, w = tid>>6, lane = tid&63, quad = lane>>4, l15 = lane&15;

    __shared__ __align__(16) f16 sA[64*72];
    __shared__ __align__(16) f16 sB[64*72];

    f32x4 D[4];
    #pragma unroll
    for (int i = 0; i < 4; ++i) D[i] = (f32x4){0.f,0.f,0.f,0.f};

    const f16* catb = cat + (size_t)b*S_*512;
    int row = tid>>2, c16 = (tid&3)*16;
    for (int i0 = 0; i0 < 512; i0 += 64){
        __syncthreads();
        *(f16x8*)&sA[row*72 + c16]     = *(const f16x8*)(cwf + (size_t)(o0+row)*512 + i0 + c16);
        *(f16x8*)&sA[row*72 + c16 + 8] = *(const f16x8*)(cwf + (size_t)(o0+row)*512 + i0 + c16 + 8);
        *(f16x8*)&sB[row*72 + c16]     = *(const f16x8*)(catb + (size_t)(s0+row)*512 + i0 + c16);
        *(f16x8*)&sB[row*72 + c16 + 8] = *(const f16x8*)(catb + (size_t)(s0+row)*512 + i0 + c16 + 8);
        __syncthreads();
        #pragma unroll
        for (int sub = 0; sub < 2; ++sub){
            f16x8 a = *(const f16x8*)&sA[(w*16+l15)*72 + sub*32 + quad*8];
            #pragma unroll
            for (int bt = 0; bt < 4; ++bt){
                f16x8 bb = *(const f16x8*)&sB[(bt*16+l15)*72 + sub*32 + quad*8];
                D[bt] = __builtin_amdgcn_mfma_f32_16x16x32_f16(a, bb, D[bt], 0,0,0);
            }
        }
    }
    #pragma unroll
    for (int r = 0; r < 4; ++r){
        int o_loc = w*16 + quad*4 + r;
        float cbv = cb[o0 + o_loc];
        size_t base = (size_t)b*C_*S_ + (size_t)(o0+o_loc)*S_ + s0;
        #pragma unroll
        for (int bt = 0; bt < 4; ++bt){
            size_t a = base + bt*16 + l15;
            out[a] = D[bt][r] + cbv + x[a];
        }
    }
}

// ---------------------------------------------------------------------------
extern "C" void kernel_launch(void* const* d_in, const int* in_sizes, int n_in,
                              void* d_out, int out_size, void* d_ws, size_t ws_size,
                              hipStream_t stream)
{
    const float* lidar = (const float*)d_in[0];
    const float* hsi   = (const float*)d_in[1];
    const float* x     = (const float*)d_in[2];
    const float* Wq = (const float*)d_in[3];  const float* bq = (const float*)d_in[4];
    const float* Wk = (const float*)d_in[5];  const float* bk = (const float*)d_in[6];
    const float* Wv = (const float*)d_in[7];  const float* bv = (const float*)d_in[8];
    const float* cw = (const float*)d_in[9];  const float* cb = (const float*)d_in[10];
    const float* rw1 = (const float*)d_in[11]; const float* rb1 = (const float*)d_in[12];
    const float* rw2 = (const float*)d_in[13]; const float* rb2 = (const float*)d_in[14];
    float* outF = (float*)d_out;
    char* ws = (char*)d_ws;
    const size_t M = 1ull<<20;

    f16* lidT = (f16*)(ws +   0*M);
    f16* hsiT = (f16*)(ws +  16*M);
    f16* Qf_l = (f16*)(ws +  32*M);
    f16* Kf_l = (f16*)(ws +  48*M);
    f16* Qf_h = (f16*)(ws +  64*M);
    f16* Kf_h = (f16*)(ws +  80*M);
    f16* Qt_l = (f16*)(ws +  96*M);
    f16* Qt_h = (f16*)(ws + 112*M);
    f16* cat  = (f16*)(ws + 128*M);   // 32 MiB
    float* g  = (float*)(ws + 160*M); // 16 KB raw channel sums
    f16* Wqf  = (f16*)(ws + 161*M);
    f16* Wkf  = (f16*)(ws + 161*M + 131072);
    f16* Wvf  = (f16*)(ws + 161*M + 262144);
    f16* cwf  = (f16*)(ws + 161*M + 393216);
    f16* Vt_l = (f16*)d_out;            // dead until k_conv; disjoint from path_prob
    f16* Vt_h = (f16*)d_out + 8388608;

    hipMemsetAsync(g, 0, 4096*sizeof(float), stream);
    k_cvtw<<<320, 256, 0, stream>>>(Wq, Wk, Wv, cw, Wqf, Wkf, Wvf, cwf);
    k_cvt<<<dim3(16,4,64), 256, 0, stream>>>(lidar, hsi, lidT, hsiT, g);
    k_mlp<<<32, 256, 0, stream>>>(g, rw1, rb1, rw2, rb2, outF);
    k_qkv<<<dim3(16,4,192), 256, 0, stream>>>(lidT, hsiT, Wqf, Wkf, Wvf, bq, bk, bv,
                                              Qf_l, Kf_l, Qf_h, Kf_h, Qt_l, Qt_h, Vt_l, Vt_h);
    k_attn<<<dim3(16,64), 256, 0, stream>>>(Qf_l, Kf_l, Qf_h, Kf_h, Qt_l, Qt_h, Vt_l, Vt_h, cat);
    k_conv<<<dim3(16,4,32), 256, 0, stream>>>(cat, cwf, cb, x, outF);
}

// Round 9
// 398.511 us; speedup vs baseline: 1.5406x; 1.5406x over previous
//
#include <hip/hip_runtime.h>
#include <stdint.h>

typedef unsigned short u16;
typedef unsigned int u32;
typedef _Float16 f16;
typedef _Float16 f16x8 __attribute__((ext_vector_type(8)));
typedef _Float16 f16x4 __attribute__((ext_vector_type(4)));
typedef float f32x4 __attribute__((ext_vector_type(4)));

#define B_ 32
#define C_ 256
#define S_ 1024

// ---------------------------------------------------------------------------
// Router MLP: path_prob = sigmoid(relu((g/1024) W1^T + b1) W2^T + b2)
// ---------------------------------------------------------------------------
__global__ __launch_bounds__(256) void k_mlp(
    const float* __restrict__ g,
    const float* __restrict__ w1, const float* __restrict__ b1,
    const float* __restrict__ w2, const float* __restrict__ b2,
    float* __restrict__ out)
{
    int b = blockIdx.x, tid = threadIdx.x;
    __shared__ float sg[512];
    __shared__ float sh[128];
    sg[tid]     = g[b*512 + tid]       * (1.0f/1024.0f);
    sg[tid+256] = g[b*512 + 256 + tid] * (1.0f/1024.0f);
    __syncthreads();
    if (tid < 128){
        float a = b1[tid];
        const float* w = w1 + (size_t)tid*512;
        #pragma unroll 4
        for (int k = 0; k < 512; k += 4){
            float4 wv = *(const float4*)(w + k);
            a += sg[k]*wv.x + sg[k+1]*wv.y + sg[k+2]*wv.z + sg[k+3]*wv.w;
        }
        sh[tid] = fmaxf(a, 0.f);
    }
    __syncthreads();
    if (tid < 4){
        float a = b2[tid];
        const float* w = w2 + (size_t)tid*128;
        for (int k = 0; k < 128; ++k) a += sh[k]*w[k];
        out[(size_t)8388608 + b*4 + tid] = 1.f/(1.f+expf(-a));
    }
}

// ---------------------------------------------------------------------------
// Weight convert fp32 -> f16 (Wq, Wk, Wv 256x256 ; cw 256x512)
// ---------------------------------------------------------------------------
__global__ __launch_bounds__(256) void k_cvtw(
    const float* __restrict__ Wq, const float* __restrict__ Wk,
    const float* __restrict__ Wv, const float* __restrict__ cw,
    f16* __restrict__ Wqf, f16* __restrict__ Wkf,
    f16* __restrict__ Wvf, f16* __restrict__ cwf)
{
    int i = (blockIdx.x*256 + threadIdx.x) * 4;
    const float* src; f16* dst; int off;
    if (i < 65536){ src = Wq; dst = Wqf; off = i; }
    else if (i < 131072){ src = Wk; dst = Wkf; off = i - 65536; }
    else if (i < 196608){ src = Wv; dst = Wvf; off = i - 131072; }
    else { src = cw; dst = cwf; off = i - 196608; }
    float4 v = *(const float4*)(src + off);
    f16x4 r = { (f16)v.x, (f16)v.y, (f16)v.z, (f16)v.w };
    *(f16x4*)(dst + off) = r;
}

// ---------------------------------------------------------------------------
// Input convert+transpose fp32 [c][s] -> f16 [s][c]  + fused channel-mean pool
// ---------------------------------------------------------------------------
__global__ __launch_bounds__(256) void k_cvt(
    const float* __restrict__ lidar, const float* __restrict__ hsi,
    f16* __restrict__ lidT, f16* __restrict__ hsiT,
    float* __restrict__ g)
{
    int z = blockIdx.z, which = z >> 5, b = z & 31;
    const float* src = (which ? hsi : lidar) + (size_t)b*C_*S_;
    f16* dst = (which ? hsiT : lidT) + (size_t)b*S_*C_;
    int tid = threadIdx.x;
    int c4 = blockIdx.y*64 + (tid&15)*4;
    int s4 = blockIdx.x*64 + (tid>>4)*4;
    float4 m[4];
    #pragma unroll
    for (int r = 0; r < 4; ++r) m[r] = *(const float4*)(src + (size_t)(c4+r)*S_ + s4);
    f16x4 t0 = { (f16)m[0].x, (f16)m[1].x, (f16)m[2].x, (f16)m[3].x };
    f16x4 t1 = { (f16)m[0].y, (f16)m[1].y, (f16)m[2].y, (f16)m[3].y };
    f16x4 t2 = { (f16)m[0].z, (f16)m[1].z, (f16)m[2].z, (f16)m[3].z };
    f16x4 t3 = { (f16)m[0].w, (f16)m[1].w, (f16)m[2].w, (f16)m[3].w };
    *(f16x4*)(dst + (size_t)(s4+0)*C_ + c4) = t0;
    *(f16x4*)(dst + (size_t)(s4+1)*C_ + c4) = t1;
    *(f16x4*)(dst + (size_t)(s4+2)*C_ + c4) = t2;
    *(f16x4*)(dst + (size_t)(s4+3)*C_ + c4) = t3;
    // fused pool
    float ps[4];
    #pragma unroll
    for (int r = 0; r < 4; ++r){
        ps[r] = m[r].x + m[r].y + m[r].z + m[r].w;
        ps[r] += __shfl_xor(ps[r], 16, 64);
        ps[r] += __shfl_xor(ps[r], 32, 64);   // wave sum over its 16 s
    }
    __shared__ float sred[4][64];
    int wv = tid>>6, lane = tid&63;
    if ((lane>>4) == 0){
        #pragma unroll
        for (int r = 0; r < 4; ++r) sred[wv][(lane&15)*4 + r] = ps[r];
    }
    __syncthreads();
    if (tid < 64){
        float v = sred[0][tid] + sred[1][tid] + sred[2][tid] + sred[3][tid];
        atomicAdd(&g[b*512 + which*256 + blockIdx.y*64 + tid], v);
    }
}

// ---------------------------------------------------------------------------
// QKV projections, f16 MFMA.  combo: 0=Q_l 1=K_l 2=V_l 3=Q_h 4=K_h 5=V_h
// ---------------------------------------------------------------------------
__global__ __launch_bounds__(256) void k_qkv(
    const f16* __restrict__ lidT, const f16* __restrict__ hsiT,
    const f16* __restrict__ Wqf, const f16* __restrict__ Wkf, const f16* __restrict__ Wvf,
    const float* __restrict__ bq, const float* __restrict__ bk, const float* __restrict__ bv,
    f16* __restrict__ Qf_l, f16* __restrict__ Kf_l,
    f16* __restrict__ Qf_h, f16* __restrict__ Kf_h,
    f16* __restrict__ Qt_l, f16* __restrict__ Qt_h,
    f16* __restrict__ Vt_l, f16* __restrict__ Vt_h)
{
    int z = blockIdx.z, combo = z >> 5, b = z & 31, ww = combo % 3;
    const f16* In = ((combo < 3) ? lidT : hsiT) + (size_t)b*S_*C_;
    const f16* Wf = (ww==0) ? Wqf : (ww==1) ? Wkf : Wvf;
    const float* bias = (ww==0) ? bq : (ww==1) ? bk : bv;
    int s0 = blockIdx.x*64, o0 = blockIdx.y*64;
    int tid = threadIdx.x, w = tid>>6, lane = tid&63, quad = lane>>4, l15 = lane&15;

    __shared__ __align__(16) f16 sA[64*72];
    __shared__ __align__(16) f16 sB[64*72];

    f32x4 D[4];
    #pragma unroll
    for (int i = 0; i < 4; ++i) D[i] = (f32x4){0.f,0.f,0.f,0.f};

    int row = tid>>2, c16 = (tid&3)*16;
    for (int c0 = 0; c0 < 256; c0 += 64){
        __syncthreads();
        *(f16x8*)&sA[row*72 + c16]     = *(const f16x8*)(In + (size_t)(s0+row)*C_ + c0 + c16);
        *(f16x8*)&sA[row*72 + c16 + 8] = *(const f16x8*)(In + (size_t)(s0+row)*C_ + c0 + c16 + 8);
        *(f16x8*)&sB[row*72 + c16]     = *(const f16x8*)(Wf + (size_t)(o0+row)*C_ + c0 + c16);
        *(f16x8*)&sB[row*72 + c16 + 8] = *(const f16x8*)(Wf + (size_t)(o0+row)*C_ + c0 + c16 + 8);
        __syncthreads();
        #pragma unroll
        for (int sub = 0; sub < 2; ++sub){
            f16x8 a = *(const f16x8*)&sA[(w*16+l15)*72 + sub*32 + quad*8];
            #pragma unroll
            for (int bt = 0; bt < 4; ++bt){
                f16x8 bb = *(const f16x8*)&sB[(bt*16+l15)*72 + sub*32 + quad*8];
                D[bt] = __builtin_amdgcn_mfma_f32_16x16x32_f16(a, bb, D[bt], 0,0,0);
            }
        }
    }
    float bi[4];
    #pragma unroll
    for (int bt = 0; bt < 4; ++bt) bi[bt] = bias[o0 + bt*16 + l15];

    if (ww == 0){
        f16* F = ((combo==0) ? Qf_l : Qf_h) + (size_t)b*S_*C_;
        #pragma unroll
        for (int bt = 0; bt < 4; ++bt)
            #pragma unroll
            for (int r = 0; r < 4; ++r)
                F[(size_t)(s0 + w*16 + quad*4 + r)*C_ + o0 + bt*16 + l15] = (f16)(D[bt][r] + bi[bt]);
    } else if (ww == 1){
        f16* F = ((combo==1) ? Kf_l : Kf_h) + (size_t)b*S_*C_;
        #pragma unroll
        for (int bt = 0; bt < 4; ++bt)
            #pragma unroll
            for (int r = 0; r < 4; ++r)
                F[(size_t)(s0 + w*16 + quad*4 + r)*C_ + o0 + bt*16 + l15] = (f16)(D[bt][r] + bi[bt]);
    }
    if (ww != 1){
        __syncthreads();
        #pragma unroll
        for (int bt = 0; bt < 4; ++bt)
            #pragma unroll
            for (int r = 0; r < 4; ++r)
                sA[(bt*16+l15)*72 + w*16 + quad*4 + r] = (f16)(D[bt][r] + bi[bt]);
        __syncthreads();
        f16* T = (combo==0) ? Qt_l : (combo==3) ? Qt_h : (combo==2) ? Vt_l : Vt_h;
        T += (size_t)b*C_*S_;
        int o_r = tid>>2, s16b = (tid&3)*16;
        *(f16x8*)(T + (size_t)(o0+o_r)*S_ + s0 + s16b)     = *(const f16x8*)&sA[o_r*72 + s16b];
        *(f16x8*)(T + (size_t)(o0+o_r)*S_ + s0 + s16b + 8) = *(const f16x8*)&sA[o_r*72 + s16b + 8];
    }
}

// ---------------------------------------------------------------------------
// QVT1[c][s] = Qt_l*Vt_h ; QVT2[c][s] = Qt_h*Vt_l   (f16 elementwise)
// ---------------------------------------------------------------------------
__global__ __launch_bounds__(256) void k_qv(
    const f16* __restrict__ Qt_l, const f16* __restrict__ Qt_h,
    const f16* __restrict__ Vt_l, const f16* __restrict__ Vt_h,
    f16* __restrict__ QVT1, f16* __restrict__ QVT2)
{
    size_t idx = (size_t)(blockIdx.x*256 + threadIdx.x) * 8;
    f16x8 a = *(const f16x8*)(Qt_l+idx);
    f16x8 b = *(const f16x8*)(Vt_h+idx);
    *(f16x8*)(QVT1+idx) = a*b;
    f16x8 c = *(const f16x8*)(Qt_h+idx);
    f16x8 d = *(const f16x8*)(Vt_l+idx);
    *(f16x8*)(QVT2+idx) = c*d;
}

// ---------------------------------------------------------------------------
// MFMA flash attention — proven best (round-2, 152.8 us / 403.2 us total):
// combined K+QVT staging, 2 barriers/tile, T14 reg prefetch (kreg/vreg only,
// fits VGPR budget), deferred rescale (THR=8), deferred l-sum, setprio.
// LDS 79.1 KB -> 2 blocks/CU.
// Closed levers (verified regressions): split-phase staging (r1, overlap
// loss), dual q-row-group (r3, VGPR spill), t-tile 32 (r4, fixed-cost wall),
// Qt*Vt in-staging fusion (r6, triple-prefetch spill: WRITE 33->511 MB).
// ---------------------------------------------------------------------------
__global__ __launch_bounds__(256, 2) void k_attn(
    const f16* __restrict__ Qf_l, const f16* __restrict__ Kf_l,
    const f16* __restrict__ Qf_h, const f16* __restrict__ Kf_h,
    const f16* __restrict__ QVT1, const f16* __restrict__ QVT2,
    f16* __restrict__ cat)
{
    int inst = blockIdx.y;
    int b = inst >> 1, which = inst & 1;
    const f16* Qf  = (which ? Qf_h : Qf_l) + (size_t)b*S_*C_;
    const f16* Kf  = (which ? Kf_h : Kf_l) + (size_t)b*S_*C_;
    const f16* QVT = (which ? QVT2 : QVT1) + (size_t)b*C_*S_;
    f16* outp = cat + (size_t)b*S_*512 + (which ? 0 : 256);
    int s0 = blockIdx.x*64;
    int tid = threadIdx.x, w = tid>>6, lane = tid&63, quad = lane>>4, l15 = lane&15;

    __shared__ __align__(16) f16 sK[64*264];    // [t][c] stride 264  (33792 B)
    __shared__ __align__(16) f16 sV[256*72];    // QVT [c][t64] stride 72 (36864 B)
    __shared__ __align__(16) f16 sPw[4][16*66]; // per-wave P scratch (8448 B)

    // Q A-frags in registers: wave w owns q-rows s0+16w .. s0+16w+15
    f16x8 qa[8];
    {
        const f16* qrow = Qf + (size_t)(s0 + w*16 + l15)*C_ + quad*8;
        #pragma unroll
        for (int i = 0; i < 8; ++i) qa[i] = *(const f16x8*)(qrow + i*32);
    }
    float mrun[4], lpart[4];
    #pragma unroll
    for (int r = 0; r < 4; ++r){ mrun[r] = -1e30f; lpart[r] = 0.f; }
    f32x4 pacc[16];
    #pragma unroll
    for (int i = 0; i < 16; ++i) pacc[i] = (f32x4){0.f,0.f,0.f,0.f};

    // prefetch registers for tile staging (T14 issue-early / write-late)
    f16x8 kreg[8], vreg[8];
    #pragma unroll
    for (int p = 0; p < 8; ++p){
        int idx = p*256 + tid;
        kreg[p] = *(const f16x8*)(Kf + (size_t)(idx>>5)*C_ + (idx&31)*8);
        vreg[p] = *(const f16x8*)(QVT + (size_t)(idx>>3)*S_ + (idx&7)*8);
    }

    for (int tt = 0; tt < 16; ++tt){
        __syncthreads();                  // prev tile's MFMA reads of sK/sV done
        #pragma unroll
        for (int p = 0; p < 8; ++p){      // write staged regs (waits vmcnt as needed)
            int idx = p*256 + tid;
            *(f16x8*)&sK[(idx>>5)*264 + (idx&31)*8] = kreg[p];
            *(f16x8*)&sV[(idx>>3)*72  + (idx&7)*8]  = vreg[p];
        }
        __syncthreads();

        // issue next tile's loads NOW; they complete under QK^T/softmax/PV
        if (tt < 15){
            int t0n = (tt+1)*64;
            #pragma unroll
            for (int p = 0; p < 8; ++p){
                int idx = p*256 + tid;
                kreg[p] = *(const f16x8*)(Kf + (size_t)(t0n + (idx>>5))*C_ + (idx&31)*8);
                vreg[p] = *(const f16x8*)(QVT + (size_t)(idx>>3)*S_ + t0n + (idx&7)*8);
            }
        }

        // ---- scores: D[16 s][64 t] per wave ----
        f32x4 sacc[4];
        #pragma unroll
        for (int bt = 0; bt < 4; ++bt) sacc[bt] = (f32x4){0.f,0.f,0.f,0.f};
        __builtin_amdgcn_s_setprio(1);
        #pragma unroll
        for (int ks = 0; ks < 8; ++ks){
            #pragma unroll
            for (int bt = 0; bt < 4; ++bt){
                f16x8 kb = *(const f16x8*)&sK[(bt*16+l15)*264 + ks*32 + quad*8];
                sacc[bt] = __builtin_amdgcn_mfma_f32_16x16x32_f16(qa[ks], kb, sacc[bt], 0,0,0);
            }
        }
        __builtin_amdgcn_s_setprio(0);

        // ---- wave-local online softmax, deferred rescale + deferred l-sum ----
        float tm[4];
        #pragma unroll
        for (int r = 0; r < 4; ++r){
            float t = fmaxf(fmaxf(sacc[0][r], sacc[1][r]), fmaxf(sacc[2][r], sacc[3][r]));
            #pragma unroll
            for (int off = 1; off < 16; off <<= 1) t = fmaxf(t, __shfl_xor(t, off, 64));
            tm[r] = t;
        }
        bool need = (tm[0] > mrun[0]+8.f) | (tm[1] > mrun[1]+8.f) |
                    (tm[2] > mrun[2]+8.f) | (tm[3] > mrun[3]+8.f);
        if (__any(need)){
            #pragma unroll
            for (int r = 0; r < 4; ++r){
                float mn = fmaxf(mrun[r], tm[r]);
                float al = __expf(mrun[r] - mn);
                mrun[r] = mn;
                lpart[r] *= al;
                #pragma unroll
                for (int cf = 0; cf < 16; ++cf) pacc[cf][r] *= al;
            }
        }
        #pragma unroll
        for (int r = 0; r < 4; ++r){
            float local = 0.f;
            #pragma unroll
            for (int bt = 0; bt < 4; ++bt){
                float p = __expf(sacc[bt][r] - mrun[r]);
                sPw[w][(quad*4+r)*66 + bt*16 + l15] = (f16)p;
                local += p;
            }
            lpart[r] += local;
        }
        // P A-frags (wave-internal LDS round-trip; no barrier)
        f16x8 pa0 = *(const f16x8*)&sPw[w][l15*66 + quad*8];
        f16x8 pa1 = *(const f16x8*)&sPw[w][l15*66 + 32 + quad*8];

        // ---- PV: D[16 s][256 c] per wave ----
        __builtin_amdgcn_s_setprio(1);
        #pragma unroll
        for (int cf = 0; cf < 16; ++cf){
            f16x8 vb0 = *(const f16x8*)&sV[(cf*16+l15)*72 + quad*8];
            f16x8 vb1 = *(const f16x8*)&sV[(cf*16+l15)*72 + 32 + quad*8];
            pacc[cf] = __builtin_amdgcn_mfma_f32_16x16x32_f16(pa0, vb0, pacc[cf], 0,0,0);
            pacc[cf] = __builtin_amdgcn_mfma_f32_16x16x32_f16(pa1, vb1, pacc[cf], 0,0,0);
        }
        __builtin_amdgcn_s_setprio(0);
    }

    // ---- epilogue: deferred l reduction + normalize ----
    #pragma unroll
    for (int r = 0; r < 4; ++r){
        #pragma unroll
        for (int off = 1; off < 16; off <<= 1) lpart[r] += __shfl_xor(lpart[r], off, 64);
    }
    #pragma unroll
    for (int r = 0; r < 4; ++r){
        int s = w*16 + quad*4 + r;
        float rl = 1.f / lpart[r];
        #pragma unroll
        for (int cf = 0; cf < 16; ++cf)
            outp[(size_t)(s0+s)*512 + cf*16 + l15] = (f16)(pacc[cf][r] * rl);
    }
}

// ---------------------------------------------------------------------------
// 1x1 conv + bias + residual, f16 MFMA
// ---------------------------------------------------------------------------
__global__ __launch_bounds__(256) void k_conv(
    const f16* __restrict__ cat, const f16* __restrict__ cwf,
    const float* __restrict__ cb, const float* __restrict__ x,
    float* __restrict__ out)
{
    int b = blockIdx.z;
    int s0 = blockIdx.x*64, o0 = blockIdx.y*64;
    int tid = threadIdx.x, w = tid>>6, lane = tid&63, quad = lane>>4, l15 = lane&15;

    __shared__ __align__(16) f16 sA[64*72];
    __shared__ __align__(16) f16 sB[64*72];

    f32x4 D[4];
    #pragma unroll
    for (int i = 0; i < 4; ++i) D[i] = (f32x4){0.f,0.f,0.f,0.f};

    const f16* catb = cat + (size_t)b*S_*512;
    int row = tid>>2, c16 = (tid&3)*16;
    for (int i0 = 0; i0 < 512; i0 += 64){
        __syncthreads();
        *(f16x8*)&sA[row*72 + c16]     = *(const f16x8*)(cwf + (size_t)(o0+row)*512 + i0 + c16);
        *(f16x8*)&sA[row*72 + c16 + 8] = *(const f16x8*)(cwf + (size_t)(o0+row)*512 + i0 + c16 + 8);
        *(f16x8*)&sB[row*72 + c16]     = *(const f16x8*)(catb + (size_t)(s0+row)*512 + i0 + c16);
        *(f16x8*)&sB[row*72 + c16 + 8] = *(const f16x8*)(catb + (size_t)(s0+row)*512 + i0 + c16 + 8);
        __syncthreads();
        #pragma unroll
        for (int sub = 0; sub < 2; ++sub){
            f16x8 a = *(const f16x8*)&sA[(w*16+l15)*72 + sub*32 + quad*8];
            #pragma unroll
            for (int bt = 0; bt < 4; ++bt){
                f16x8 bb = *(const f16x8*)&sB[(bt*16+l15)*72 + sub*32 + quad*8];
                D[bt] = __builtin_amdgcn_mfma_f32_16x16x32_f16(a, bb, D[bt], 0,0,0);
            }
        }
    }
    #pragma unroll
    for (int r = 0; r < 4; ++r){
        int o_loc = w*16 + quad*4 + r;
        float cbv = cb[o0 + o_loc];
        size_t base = (size_t)b*C_*S_ + (size_t)(o0+o_loc)*S_ + s0;
        #pragma unroll
        for (int bt = 0; bt < 4; ++bt){
            size_t a = base + bt*16 + l15;
            out[a] = D[bt][r] + cbv + x[a];
        }
    }
}

// ---------------------------------------------------------------------------
extern "C" void kernel_launch(void* const* d_in, const int* in_sizes, int n_in,
                              void* d_out, int out_size, void* d_ws, size_t ws_size,
                              hipStream_t stream)
{
    const float* lidar = (const float*)d_in[0];
    const float* hsi   = (const float*)d_in[1];
    const float* x     = (const float*)d_in[2];
    const float* Wq = (const float*)d_in[3];  const float* bq = (const float*)d_in[4];
    const float* Wk = (const float*)d_in[5];  const float* bk = (const float*)d_in[6];
    const float* Wv = (const float*)d_in[7];  const float* bv = (const float*)d_in[8];
    const float* cw = (const float*)d_in[9];  const float* cb = (const float*)d_in[10];
    const float* rw1 = (const float*)d_in[11]; const float* rb1 = (const float*)d_in[12];
    const float* rw2 = (const float*)d_in[13]; const float* rb2 = (const float*)d_in[14];
    float* outF = (float*)d_out;
    char* ws = (char*)d_ws;
    const size_t M = 1ull<<20;

    f16* lidT = (f16*)(ws +   0*M);   // alias: QVT1 after k_qkv
    f16* hsiT = (f16*)(ws +  16*M);   // alias: QVT2 after k_qkv
    f16* Qf_l = (f16*)(ws +  32*M);
    f16* Kf_l = (f16*)(ws +  48*M);
    f16* Qf_h = (f16*)(ws +  64*M);
    f16* Kf_h = (f16*)(ws +  80*M);
    f16* Qt_l = (f16*)(ws +  96*M);
    f16* Qt_h = (f16*)(ws + 112*M);
    f16* cat  = (f16*)(ws + 128*M);   // 32 MiB
    float* g  = (float*)(ws + 160*M); // 16 KB raw channel sums
    f16* Wqf  = (f16*)(ws + 161*M);
    f16* Wkf  = (f16*)(ws + 161*M + 131072);
    f16* Wvf  = (f16*)(ws + 161*M + 262144);
    f16* cwf  = (f16*)(ws + 161*M + 393216);
    f16* QVT1 = lidT;
    f16* QVT2 = hsiT;
    f16* Vt_l = (f16*)d_out;            // dead until k_conv; disjoint from path_prob
    f16* Vt_h = (f16*)d_out + 8388608;

    hipMemsetAsync(g, 0, 4096*sizeof(float), stream);
    k_cvtw<<<320, 256, 0, stream>>>(Wq, Wk, Wv, cw, Wqf, Wkf, Wvf, cwf);
    k_cvt<<<dim3(16,4,64), 256, 0, stream>>>(lidar, hsi, lidT, hsiT, g);
    k_mlp<<<32, 256, 0, stream>>>(g, rw1, rb1, rw2, rb2, outF);
    k_qkv<<<dim3(16,4,192), 256, 0, stream>>>(lidT, hsiT, Wqf, Wkf, Wvf, bq, bk, bv,
                                              Qf_l, Kf_l, Qf_h, Kf_h, Qt_l, Qt_h, Vt_l, Vt_h);
    k_qv<<<4096, 256, 0, stream>>>(Qt_l, Qt_h, Vt_l, Vt_h, QVT1, QVT2);
    k_attn<<<dim3(16,64), 256, 0, stream>>>(Qf_l, Kf_l, Qf_h, Kf_h, QVT1, QVT2, cat);
    k_conv<<<dim3(16,4,32), 256, 0, stream>>>(cat, cwf, cb, x, outF);
}

// Round 10
// 397.462 us; speedup vs baseline: 1.5446x; 1.0026x over previous
//
#include <hip/hip_runtime.h>
#include <stdint.h>

typedef unsigned short u16;
typedef unsigned int u32;
typedef _Float16 f16;
typedef _Float16 f16x8 __attribute__((ext_vector_type(8)));
typedef _Float16 f16x4 __attribute__((ext_vector_type(4)));
typedef float f32x4 __attribute__((ext_vector_type(4)));

#define B_ 32
#define C_ 256
#define S_ 1024

// ---------------------------------------------------------------------------
// Router MLP: path_prob = sigmoid(relu((g/1024) W1^T + b1) W2^T + b2)
// ---------------------------------------------------------------------------
__global__ __launch_bounds__(256) void k_mlp(
    const float* __restrict__ g,
    const float* __restrict__ w1, const float* __restrict__ b1,
    const float* __restrict__ w2, const float* __restrict__ b2,
    float* __restrict__ out)
{
    int b = blockIdx.x, tid = threadIdx.x;
    __shared__ float sg[512];
    __shared__ float sh[128];
    sg[tid]     = g[b*512 + tid]       * (1.0f/1024.0f);
    sg[tid+256] = g[b*512 + 256 + tid] * (1.0f/1024.0f);
    __syncthreads();
    if (tid < 128){
        float a = b1[tid];
        const float* w = w1 + (size_t)tid*512;
        #pragma unroll 4
        for (int k = 0; k < 512; k += 4){
            float4 wv = *(const float4*)(w + k);
            a += sg[k]*wv.x + sg[k+1]*wv.y + sg[k+2]*wv.z + sg[k+3]*wv.w;
        }
        sh[tid] = fmaxf(a, 0.f);
    }
    __syncthreads();
    if (tid < 4){
        float a = b2[tid];
        const float* w = w2 + (size_t)tid*128;
        for (int k = 0; k < 128; ++k) a += sh[k]*w[k];
        out[(size_t)8388608 + b*4 + tid] = 1.f/(1.f+expf(-a));
    }
}

// ---------------------------------------------------------------------------
// Weight convert fp32 -> f16 (Wq, Wk, Wv 256x256 ; cw 256x512)
// ---------------------------------------------------------------------------
__global__ __launch_bounds__(256) void k_cvtw(
    const float* __restrict__ Wq, const float* __restrict__ Wk,
    const float* __restrict__ Wv, const float* __restrict__ cw,
    f16* __restrict__ Wqf, f16* __restrict__ Wkf,
    f16* __restrict__ Wvf, f16* __restrict__ cwf)
{
    int i = (blockIdx.x*256 + threadIdx.x) * 4;
    const float* src; f16* dst; int off;
    if (i < 65536){ src = Wq; dst = Wqf; off = i; }
    else if (i < 131072){ src = Wk; dst = Wkf; off = i - 65536; }
    else if (i < 196608){ src = Wv; dst = Wvf; off = i - 131072; }
    else { src = cw; dst = cwf; off = i - 196608; }
    float4 v = *(const float4*)(src + off);
    f16x4 r = { (f16)v.x, (f16)v.y, (f16)v.z, (f16)v.w };
    *(f16x4*)(dst + off) = r;
}

// ---------------------------------------------------------------------------
// Input convert+transpose fp32 [c][s] -> f16 [s][c]  + fused channel-mean pool
// ---------------------------------------------------------------------------
__global__ __launch_bounds__(256) void k_cvt(
    const float* __restrict__ lidar, const float* __restrict__ hsi,
    f16* __restrict__ lidT, f16* __restrict__ hsiT,
    float* __restrict__ g)
{
    int z = blockIdx.z, which = z >> 5, b = z & 31;
    const float* src = (which ? hsi : lidar) + (size_t)b*C_*S_;
    f16* dst = (which ? hsiT : lidT) + (size_t)b*S_*C_;
    int tid = threadIdx.x;
    int c4 = blockIdx.y*64 + (tid&15)*4;
    int s4 = blockIdx.x*64 + (tid>>4)*4;
    float4 m[4];
    #pragma unroll
    for (int r = 0; r < 4; ++r) m[r] = *(const float4*)(src + (size_t)(c4+r)*S_ + s4);
    f16x4 t0 = { (f16)m[0].x, (f16)m[1].x, (f16)m[2].x, (f16)m[3].x };
    f16x4 t1 = { (f16)m[0].y, (f16)m[1].y, (f16)m[2].y, (f16)m[3].y };
    f16x4 t2 = { (f16)m[0].z, (f16)m[1].z, (f16)m[2].z, (f16)m[3].z };
    f16x4 t3 = { (f16)m[0].w, (f16)m[1].w, (f16)m[2].w, (f16)m[3].w };
    *(f16x4*)(dst + (size_t)(s4+0)*C_ + c4) = t0;
    *(f16x4*)(dst + (size_t)(s4+1)*C_ + c4) = t1;
    *(f16x4*)(dst + (size_t)(s4+2)*C_ + c4) = t2;
    *(f16x4*)(dst + (size_t)(s4+3)*C_ + c4) = t3;
    // fused pool
    float ps[4];
    #pragma unroll
    for (int r = 0; r < 4; ++r){
        ps[r] = m[r].x + m[r].y + m[r].z + m[r].w;
        ps[r] += __shfl_xor(ps[r], 16, 64);
        ps[r] += __shfl_xor(ps[r], 32, 64);   // wave sum over its 16 s
    }
    __shared__ float sred[4][64];
    int wv = tid>>6, lane = tid&63;
    if ((lane>>4) == 0){
        #pragma unroll
        for (int r = 0; r < 4; ++r) sred[wv][(lane&15)*4 + r] = ps[r];
    }
    __syncthreads();
    if (tid < 64){
        float v = sred[0][tid] + sred[1][tid] + sred[2][tid] + sred[3][tid];
        atomicAdd(&g[b*512 + which*256 + blockIdx.y*64 + tid], v);
    }
}

// ---------------------------------------------------------------------------
// QKV projections, f16 MFMA.  combo: 0=Q_l 1=K_l 2=V_l 3=Q_h 4=K_h 5=V_h
// ---------------------------------------------------------------------------
__global__ __launch_bounds__(256) void k_qkv(
    const f16* __restrict__ lidT, const f16* __restrict__ hsiT,
    const f16* __restrict__ Wqf, const f16* __restrict__ Wkf, const f16* __restrict__ Wvf,
    const float* __restrict__ bq, const float* __restrict__ bk, const float* __restrict__ bv,
    f16* __restrict__ Qf_l, f16* __restrict__ Kf_l,
    f16* __restrict__ Qf_h, f16* __restrict__ Kf_h,
    f16* __restrict__ Qt_l, f16* __restrict__ Qt_h,
    f16* __restrict__ Vt_l, f16* __restrict__ Vt_h)
{
    int z = blockIdx.z, combo = z >> 5, b = z & 31, ww = combo % 3;
    const f16* In = ((combo < 3) ? lidT : hsiT) + (size_t)b*S_*C_;
    const f16* Wf = (ww==0) ? Wqf : (ww==1) ? Wkf : Wvf;
    const float* bias = (ww==0) ? bq : (ww==1) ? bk : bv;
    int s0 = blockIdx.x*64, o0 = blockIdx.y*64;
    int tid = threadIdx.x, w = tid>>6, lane = tid&63, quad = lane>>4, l15 = lane&15;

    __shared__ __align__(16) f16 sA[64*72];
    __shared__ __align__(16) f16 sB[64*72];

    f32x4 D[4];
    #pragma unroll
    for (int i = 0; i < 4; ++i) D[i] = (f32x4){0.f,0.f,0.f,0.f};

    int row = tid>>2, c16 = (tid&3)*16;
    for (int c0 = 0; c0 < 256; c0 += 64){
        __syncthreads();
        *(f16x8*)&sA[row*72 + c16]     = *(const f16x8*)(In + (size_t)(s0+row)*C_ + c0 + c16);
        *(f16x8*)&sA[row*72 + c16 + 8] = *(const f16x8*)(In + (size_t)(s0+row)*C_ + c0 + c16 + 8);
        *(f16x8*)&sB[row*72 + c16]     = *(const f16x8*)(Wf + (size_t)(o0+row)*C_ + c0 + c16);
        *(f16x8*)&sB[row*72 + c16 + 8] = *(const f16x8*)(Wf + (size_t)(o0+row)*C_ + c0 + c16 + 8);
        __syncthreads();
        #pragma unroll
        for (int sub = 0; sub < 2; ++sub){
            f16x8 a = *(const f16x8*)&sA[(w*16+l15)*72 + sub*32 + quad*8];
            #pragma unroll
            for (int bt = 0; bt < 4; ++bt){
                f16x8 bb = *(const f16x8*)&sB[(bt*16+l15)*72 + sub*32 + quad*8];
                D[bt] = __builtin_amdgcn_mfma_f32_16x16x32_f16(a, bb, D[bt], 0,0,0);
            }
        }
    }
    float bi[4];
    #pragma unroll
    for (int bt = 0; bt < 4; ++bt) bi[bt] = bias[o0 + bt*16 + l15];

    if (ww == 0){
        f16* F = ((combo==0) ? Qf_l : Qf_h) + (size_t)b*S_*C_;
        #pragma unroll
        for (int bt = 0; bt < 4; ++bt)
            #pragma unroll
            for (int r = 0; r < 4; ++r)
                F[(size_t)(s0 + w*16 + quad*4 + r)*C_ + o0 + bt*16 + l15] = (f16)(D[bt][r] + bi[bt]);
    } else if (ww == 1){
        f16* F = ((combo==1) ? Kf_l : Kf_h) + (size_t)b*S_*C_;
        #pragma unroll
        for (int bt = 0; bt < 4; ++bt)
            #pragma unroll
            for (int r = 0; r < 4; ++r)
                F[(size_t)(s0 + w*16 + quad*4 + r)*C_ + o0 + bt*16 + l15] = (f16)(D[bt][r] + bi[bt]);
    }
    if (ww != 1){
        __syncthreads();
        #pragma unroll
        for (int bt = 0; bt < 4; ++bt)
            #pragma unroll
            for (int r = 0; r < 4; ++r)
                sA[(bt*16+l15)*72 + w*16 + quad*4 + r] = (f16)(D[bt][r] + bi[bt]);
        __syncthreads();
        f16* T = (combo==0) ? Qt_l : (combo==3) ? Qt_h : (combo==2) ? Vt_l : Vt_h;
        T += (size_t)b*C_*S_;
        int o_r = tid>>2, s16b = (tid&3)*16;
        *(f16x8*)(T + (size_t)(o0+o_r)*S_ + s0 + s16b)     = *(const f16x8*)&sA[o_r*72 + s16b];
        *(f16x8*)(T + (size_t)(o0+o_r)*S_ + s0 + s16b + 8) = *(const f16x8*)&sA[o_r*72 + s16b + 8];
    }
}

// ---------------------------------------------------------------------------
// QVT1[c][s] = Qt_l*Vt_h ; QVT2[c][s] = Qt_h*Vt_l   (f16 elementwise)
// ---------------------------------------------------------------------------
__global__ __launch_bounds__(256) void k_qv(
    const f16* __restrict__ Qt_l, const f16* __restrict__ Qt_h,
    const f16* __restrict__ Vt_l, const f16* __restrict__ Vt_h,
    f16* __restrict__ QVT1, f16* __restrict__ QVT2)
{
    size_t idx = (size_t)(blockIdx.x*256 + threadIdx.x) * 8;
    f16x8 a = *(const f16x8*)(Qt_l+idx);
    f16x8 b = *(const f16x8*)(Vt_h+idx);
    *(f16x8*)(QVT1+idx) = a*b;
    f16x8 c = *(const f16x8*)(Qt_h+idx);
    f16x8 d = *(const f16x8*)(Vt_l+idx);
    *(f16x8*)(QVT2+idx) = c*d;
}

// ---------------------------------------------------------------------------
// MFMA flash attention — round-2 proven schedule + T1 XCD-contiguous block
// remap (single-variable experiment this round):
//   lin = x + 16*y is the HW dispatch order (round-robined n%8 across XCDs).
//   L = (lin&7)*128 + lin>>3 gives each XCD a CONTIGUOUS chunk of logical
//   work -> the 16 s-blocks sharing one (b,which) instance's K/QVT stay on
//   one XCD's L2 (resident window ~4 instances = 6 MB vs 32 instances =
//   48 MB before). Bijective since 1024 % 8 == 0 (ERRATA #11 guard).
// Everything else identical to the verified 152.1 us kernel.
// ---------------------------------------------------------------------------
__global__ __launch_bounds__(256, 2) void k_attn(
    const f16* __restrict__ Qf_l, const f16* __restrict__ Kf_l,
    const f16* __restrict__ Qf_h, const f16* __restrict__ Kf_h,
    const f16* __restrict__ QVT1, const f16* __restrict__ QVT2,
    f16* __restrict__ cat)
{
    int lin  = blockIdx.y*16 + blockIdx.x;     // hw dispatch order (x fastest)
    int L    = (lin & 7)*128 + (lin >> 3);     // XCD-contiguous, bijective
    int inst = L >> 4;
    int s0   = (L & 15)*64;
    int b = inst >> 1, which = inst & 1;
    const f16* Qf  = (which ? Qf_h : Qf_l) + (size_t)b*S_*C_;
    const f16* Kf  = (which ? Kf_h : Kf_l) + (size_t)b*S_*C_;
    const f16* QVT = (which ? QVT2 : QVT1) + (size_t)b*C_*S_;
    f16* outp = cat + (size_t)b*S_*512 + (which ? 0 : 256);
    int tid = threadIdx.x, w = tid>>6, lane = tid&63, quad = lane>>4, l15 = lane&15;

    __shared__ __align__(16) f16 sK[64*264];    // [t][c] stride 264  (33792 B)
    __shared__ __align__(16) f16 sV[256*72];    // QVT [c][t64] stride 72 (36864 B)
    __shared__ __align__(16) f16 sPw[4][16*66]; // per-wave P scratch (8448 B)

    // Q A-frags in registers: wave w owns q-rows s0+16w .. s0+16w+15
    f16x8 qa[8];
    {
        const f16* qrow = Qf + (size_t)(s0 + w*16 + l15)*C_ + quad*8;
        #pragma unroll
        for (int i = 0; i < 8; ++i) qa[i] = *(const f16x8*)(qrow + i*32);
    }
    float mrun[4], lpart[4];
    #pragma unroll
    for (int r = 0; r < 4; ++r){ mrun[r] = -1e30f; lpart[r] = 0.f; }
    f32x4 pacc[16];
    #pragma unroll
    for (int i = 0; i < 16; ++i) pacc[i] = (f32x4){0.f,0.f,0.f,0.f};

    // prefetch registers for tile staging (T14 issue-early / write-late)
    f16x8 kreg[8], vreg[8];
    #pragma unroll
    for (int p = 0; p < 8; ++p){
        int idx = p*256 + tid;
        kreg[p] = *(const f16x8*)(Kf + (size_t)(idx>>5)*C_ + (idx&31)*8);
        vreg[p] = *(const f16x8*)(QVT + (size_t)(idx>>3)*S_ + (idx&7)*8);
    }

    for (int tt = 0; tt < 16; ++tt){
        __syncthreads();                  // prev tile's MFMA reads of sK/sV done
        #pragma unroll
        for (int p = 0; p < 8; ++p){      // write staged regs (waits vmcnt as needed)
            int idx = p*256 + tid;
            *(f16x8*)&sK[(idx>>5)*264 + (idx&31)*8] = kreg[p];
            *(f16x8*)&sV[(idx>>3)*72  + (idx&7)*8]  = vreg[p];
        }
        __syncthreads();

        // issue next tile's loads NOW; they complete under QK^T/softmax/PV
        if (tt < 15){
            int t0n = (tt+1)*64;
            #pragma unroll
            for (int p = 0; p < 8; ++p){
                int idx = p*256 + tid;
                kreg[p] = *(const f16x8*)(Kf + (size_t)(t0n + (idx>>5))*C_ + (idx&31)*8);
                vreg[p] = *(const f16x8*)(QVT + (size_t)(idx>>3)*S_ + t0n + (idx&7)*8);
            }
        }

        // ---- scores: D[16 s][64 t] per wave ----
        f32x4 sacc[4];
        #pragma unroll
        for (int bt = 0; bt < 4; ++bt) sacc[bt] = (f32x4){0.f,0.f,0.f,0.f};
        __builtin_amdgcn_s_setprio(1);
        #pragma unroll
        for (int ks = 0; ks < 8; ++ks){
            #pragma unroll
            for (int bt = 0; bt < 4; ++bt){
                f16x8 kb = *(const f16x8*)&sK[(bt*16+l15)*264 + ks*32 + quad*8];
                sacc[bt] = __builtin_amdgcn_mfma_f32_16x16x32_f16(qa[ks], kb, sacc[bt], 0,0,0);
            }
        }
        __builtin_amdgcn_s_setprio(0);

        // ---- wave-local online softmax, deferred rescale + deferred l-sum ----
        float tm[4];
        #pragma unroll
        for (int r = 0; r < 4; ++r){
            float t = fmaxf(fmaxf(sacc[0][r], sacc[1][r]), fmaxf(sacc[2][r], sacc[3][r]));
            #pragma unroll
            for (int off = 1; off < 16; off <<= 1) t = fmaxf(t, __shfl_xor(t, off, 64));
            tm[r] = t;
        }
        bool need = (tm[0] > mrun[0]+8.f) | (tm[1] > mrun[1]+8.f) |
                    (tm[2] > mrun[2]+8.f) | (tm[3] > mrun[3]+8.f);
        if (__any(need)){
            #pragma unroll
            for (int r = 0; r < 4; ++r){
                float mn = fmaxf(mrun[r], tm[r]);
                float al = __expf(mrun[r] - mn);
                mrun[r] = mn;
                lpart[r] *= al;
                #pragma unroll
                for (int cf = 0; cf < 16; ++cf) pacc[cf][r] *= al;
            }
        }
        #pragma unroll
        for (int r = 0; r < 4; ++r){
            float local = 0.f;
            #pragma unroll
            for (int bt = 0; bt < 4; ++bt){
                float p = __expf(sacc[bt][r] - mrun[r]);
                sPw[w][(quad*4+r)*66 + bt*16 + l15] = (f16)p;
                local += p;
            }
            lpart[r] += local;
        }
        // P A-frags (wave-internal LDS round-trip; no barrier)
        f16x8 pa0 = *(const f16x8*)&sPw[w][l15*66 + quad*8];
        f16x8 pa1 = *(const f16x8*)&sPw[w][l15*66 + 32 + quad*8];

        // ---- PV: D[16 s][256 c] per wave ----
        __builtin_amdgcn_s_setprio(1);
        #pragma unroll
        for (int cf = 0; cf < 16; ++cf){
            f16x8 vb0 = *(const f16x8*)&sV[(cf*16+l15)*72 + quad*8];
            f16x8 vb1 = *(const f16x8*)&sV[(cf*16+l15)*72 + 32 + quad*8];
            pacc[cf] = __builtin_amdgcn_mfma_f32_16x16x32_f16(pa0, vb0, pacc[cf], 0,0,0);
            pacc[cf] = __builtin_amdgcn_mfma_f32_16x16x32_f16(pa1, vb1, pacc[cf], 0,0,0);
        }
        __builtin_amdgcn_s_setprio(0);
    }

    // ---- epilogue: deferred l reduction + normalize ----
    #pragma unroll
    for (int r = 0; r < 4; ++r){
        #pragma unroll
        for (int off = 1; off < 16; off <<= 1) lpart[r] += __shfl_xor(lpart[r], off, 64);
    }
    #pragma unroll
    for (int r = 0; r < 4; ++r){
        int s = w*16 + quad*4 + r;
        float rl = 1.f / lpart[r];
        #pragma unroll
        for (int cf = 0; cf < 16; ++cf)
            outp[(size_t)(s0+s)*512 + cf*16 + l15] = (f16)(pacc[cf][r] * rl);
    }
}

// ---------------------------------------------------------------------------
// 1x1 conv + bias + residual, f16 MFMA
// ---------------------------------------------------------------------------
__global__ __launch_bounds__(256) void k_conv(
    const f16* __restrict__ cat, const f16* __restrict__ cwf,
    const float* __restrict__ cb, const float* __restrict__ x,
    float* __restrict__ out)
{
    int b = blockIdx.z;
    int s0 = blockIdx.x*64, o0 = blockIdx.y*64;
    int tid = threadIdx.x, w = tid>>6, lane = tid&63, quad = lane>>4, l15 = lane&15;

    __shared__ __align__(16) f16 sA[64*72];
    __shared__ __align__(16) f16 sB[64*72];

    f32x4 D[4];
    #pragma unroll
    for (int i = 0; i < 4; ++i) D[i] = (f32x4){0.f,0.f,0.f,0.f};

    const f16* catb = cat + (size_t)b*S_*512;
    int row = tid>>2, c16 = (tid&3)*16;
    for (int i0 = 0; i0 < 512; i0 += 64){
        __syncthreads();
        *(f16x8*)&sA[row*72 + c16]     = *(const f16x8*)(cwf + (size_t)(o0+row)*512 + i0 + c16);
        *(f16x8*)&sA[row*72 + c16 + 8] = *(const f16x8*)(cwf + (size_t)(o0+row)*512 + i0 + c16 + 8);
        *(f16x8*)&sB[row*72 + c16]     = *(const f16x8*)(catb + (size_t)(s0+row)*512 + i0 + c16);
        *(f16x8*)&sB[row*72 + c16 + 8] = *(const f16x8*)(catb + (size_t)(s0+row)*512 + i0 + c16 + 8);
        __syncthreads();
        #pragma unroll
        for (int sub = 0; sub < 2; ++sub){
            f16x8 a = *(const f16x8*)&sA[(w*16+l15)*72 + sub*32 + quad*8];
            #pragma unroll
            for (int bt = 0; bt < 4; ++bt){
                f16x8 bb = *(const f16x8*)&sB[(bt*16+l15)*72 + sub*32 + quad*8];
                D[bt] = __builtin_amdgcn_mfma_f32_16x16x32_f16(a, bb, D[bt], 0,0,0);
            }
        }
    }
    #pragma unroll
    for (int r = 0; r < 4; ++r){
        int o_loc = w*16 + quad*4 + r;
        float cbv = cb[o0 + o_loc];
        size_t base = (size_t)b*C_*S_ + (size_t)(o0+o_loc)*S_ + s0;
        #pragma unroll
        for (int bt = 0; bt < 4; ++bt){
            size_t a = base + bt*16 + l15;
            out[a] = D[bt][r] + cbv + x[a];
        }
    }
}

// ---------------------------------------------------------------------------
extern "C" void kernel_launch(void* const* d_in, const int* in_sizes, int n_in,
                              void* d_out, int out_size, void* d_ws, size_t ws_size,
                              hipStream_t stream)
{
    const float* lidar = (const float*)d_in[0];
    const float* hsi   = (const float*)d_in[1];
    const float* x     = (const float*)d_in[2];
    const float* Wq = (const float*)d_in[3];  const float* bq = (const float*)d_in[4];
    const float* Wk = (const float*)d_in[5];  const float* bk = (const float*)d_in[6];
    const float* Wv = (const float*)d_in[7];  const float* bv = (const float*)d_in[8];
    const float* cw = (const float*)d_in[9];  const float* cb = (const float*)d_in[10];
    const float* rw1 = (const float*)d_in[11]; const float* rb1 = (const float*)d_in[12];
    const float* rw2 = (const float*)d_in[13]; const float* rb2 = (const float*)d_in[14];
    float* outF = (float*)d_out;
    char* ws = (char*)d_ws;
    const size_t M = 1ull<<20;

    f16* lidT = (f16*)(ws +   0*M);   // alias: QVT1 after k_qkv
    f16* hsiT = (f16*)(ws +  16*M);   // alias: QVT2 after k_qkv
    f16* Qf_l = (f16*)(ws +  32*M);
    f16* Kf_l = (f16*)(ws +  48*M);
    f16* Qf_h = (f16*)(ws +  64*M);
    f16* Kf_h = (f16*)(ws +  80*M);
    f16* Qt_l = (f16*)(ws +  96*M);
    f16* Qt_h = (f16*)(ws + 112*M);
    f16* cat  = (f16*)(ws + 128*M);   // 32 MiB
    float* g  = (float*)(ws + 160*M); // 16 KB raw channel sums
    f16* Wqf  = (f16*)(ws + 161*M);
    f16* Wkf  = (f16*)(ws + 161*M + 131072);
    f16* Wvf  = (f16*)(ws + 161*M + 262144);
    f16* cwf  = (f16*)(ws + 161*M + 393216);
    f16* QVT1 = lidT;
    f16* QVT2 = hsiT;
    f16* Vt_l = (f16*)d_out;            // dead until k_conv; disjoint from path_prob
    f16* Vt_h = (f16*)d_out + 8388608;

    hipMemsetAsync(g, 0, 4096*sizeof(float), stream);
    k_cvtw<<<320, 256, 0, stream>>>(Wq, Wk, Wv, cw, Wqf, Wkf, Wvf, cwf);
    k_cvt<<<dim3(16,4,64), 256, 0, stream>>>(lidar, hsi, lidT, hsiT, g);
    k_mlp<<<32, 256, 0, stream>>>(g, rw1, rb1, rw2, rb2, outF);
    k_qkv<<<dim3(16,4,192), 256, 0, stream>>>(lidT, hsiT, Wqf, Wkf, Wvf, bq, bk, bv,
                                              Qf_l, Kf_l, Qf_h, Kf_h, Qt_l, Qt_h, Vt_l, Vt_h);
    k_qv<<<4096, 256, 0, stream>>>(Qt_l, Qt_h, Vt_l, Vt_h, QVT1, QVT2);
    k_attn<<<dim3(16,64), 256, 0, stream>>>(Qf_l, Kf_l, Qf_h, Kf_h, QVT1, QVT2, cat);
    k_conv<<<dim3(16,4,32), 256, 0, stream>>>(cat, cwf, cb, x, outF);
}

// Round 11
// 388.052 us; speedup vs baseline: 1.5821x; 1.0243x over previous
//
#include <hip/hip_runtime.h>
#include <stdint.h>

typedef unsigned short u16;
typedef unsigned int u32;
typedef _Float16 f16;
typedef _Float16 f16x8 __attribute__((ext_vector_type(8)));
typedef _Float16 f16x4 __attribute__((ext_vector_type(4)));
typedef float f32x4 __attribute__((ext_vector_type(4)));

#define B_ 32
#define C_ 256
#define S_ 1024

// ---------------------------------------------------------------------------
// Router MLP: path_prob = sigmoid(relu((g/1024) W1^T + b1) W2^T + b2)
// ---------------------------------------------------------------------------
__global__ __launch_bounds__(256) void k_mlp(
    const float* __restrict__ g,
    const float* __restrict__ w1, const float* __restrict__ b1,
    const float* __restrict__ w2, const float* __restrict__ b2,
    float* __restrict__ out)
{
    int b = blockIdx.x, tid = threadIdx.x;
    __shared__ float sg[512];
    __shared__ float sh[128];
    sg[tid]     = g[b*512 + tid]       * (1.0f/1024.0f);
    sg[tid+256] = g[b*512 + 256 + tid] * (1.0f/1024.0f);
    __syncthreads();
    if (tid < 128){
        float a = b1[tid];
        const float* w = w1 + (size_t)tid*512;
        #pragma unroll 4
        for (int k = 0; k < 512; k += 4){
            float4 wv = *(const float4*)(w + k);
            a += sg[k]*wv.x + sg[k+1]*wv.y + sg[k+2]*wv.z + sg[k+3]*wv.w;
        }
        sh[tid] = fmaxf(a, 0.f);
    }
    __syncthreads();
    if (tid < 4){
        float a = b2[tid];
        const float* w = w2 + (size_t)tid*128;
        for (int k = 0; k < 128; ++k) a += sh[k]*w[k];
        out[(size_t)8388608 + b*4 + tid] = 1.f/(1.f+expf(-a));
    }
}

// ---------------------------------------------------------------------------
// Weight convert fp32 -> f16 (Wq, Wk, Wv 256x256 ; cw 256x512)
// ---------------------------------------------------------------------------
__global__ __launch_bounds__(256) void k_cvtw(
    const float* __restrict__ Wq, const float* __restrict__ Wk,
    const float* __restrict__ Wv, const float* __restrict__ cw,
    f16* __restrict__ Wqf, f16* __restrict__ Wkf,
    f16* __restrict__ Wvf, f16* __restrict__ cwf)
{
    int i = (blockIdx.x*256 + threadIdx.x) * 4;
    const float* src; f16* dst; int off;
    if (i < 65536){ src = Wq; dst = Wqf; off = i; }
    else if (i < 131072){ src = Wk; dst = Wkf; off = i - 65536; }
    else if (i < 196608){ src = Wv; dst = Wvf; off = i - 131072; }
    else { src = cw; dst = cwf; off = i - 196608; }
    float4 v = *(const float4*)(src + off);
    f16x4 r = { (f16)v.x, (f16)v.y, (f16)v.z, (f16)v.w };
    *(f16x4*)(dst + off) = r;
}

// ---------------------------------------------------------------------------
// Input convert+transpose fp32 [c][s] -> f16 [s][c]  + fused channel-mean pool
// ---------------------------------------------------------------------------
__global__ __launch_bounds__(256) void k_cvt(
    const float* __restrict__ lidar, const float* __restrict__ hsi,
    f16* __restrict__ lidT, f16* __restrict__ hsiT,
    float* __restrict__ g)
{
    int z = blockIdx.z, which = z >> 5, b = z & 31;
    const float* src = (which ? hsi : lidar) + (size_t)b*C_*S_;
    f16* dst = (which ? hsiT : lidT) + (size_t)b*S_*C_;
    int tid = threadIdx.x;
    int c4 = blockIdx.y*64 + (tid&15)*4;
    int s4 = blockIdx.x*64 + (tid>>4)*4;
    float4 m[4];
    #pragma unroll
    for (int r = 0; r < 4; ++r) m[r] = *(const float4*)(src + (size_t)(c4+r)*S_ + s4);
    f16x4 t0 = { (f16)m[0].x, (f16)m[1].x, (f16)m[2].x, (f16)m[3].x };
    f16x4 t1 = { (f16)m[0].y, (f16)m[1].y, (f16)m[2].y, (f16)m[3].y };
    f16x4 t2 = { (f16)m[0].z, (f16)m[1].z, (f16)m[2].z, (f16)m[3].z };
    f16x4 t3 = { (f16)m[0].w, (f16)m[1].w, (f16)m[2].w, (f16)m[3].w };
    *(f16x4*)(dst + (size_t)(s4+0)*C_ + c4) = t0;
    *(f16x4*)(dst + (size_t)(s4+1)*C_ + c4) = t1;
    *(f16x4*)(dst + (size_t)(s4+2)*C_ + c4) = t2;
    *(f16x4*)(dst + (size_t)(s4+3)*C_ + c4) = t3;
    // fused pool
    float ps[4];
    #pragma unroll
    for (int r = 0; r < 4; ++r){
        ps[r] = m[r].x + m[r].y + m[r].z + m[r].w;
        ps[r] += __shfl_xor(ps[r], 16, 64);
        ps[r] += __shfl_xor(ps[r], 32, 64);   // wave sum over its 16 s
    }
    __shared__ float sred[4][64];
    int wv = tid>>6, lane = tid&63;
    if ((lane>>4) == 0){
        #pragma unroll
        for (int r = 0; r < 4; ++r) sred[wv][(lane&15)*4 + r] = ps[r];
    }
    __syncthreads();
    if (tid < 64){
        float v = sred[0][tid] + sred[1][tid] + sred[2][tid] + sred[3][tid];
        atomicAdd(&g[b*512 + which*256 + blockIdx.y*64 + tid], v);
    }
}

// ---------------------------------------------------------------------------
// QKV projections, f16 MFMA.  combo: 0=Q_l 1=K_l 2=V_l 3=Q_h 4=K_h 5=V_h
// ---------------------------------------------------------------------------
__global__ __launch_bounds__(256) void k_qkv(
    const f16* __restrict__ lidT, const f16* __restrict__ hsiT,
    const f16* __restrict__ Wqf, const f16* __restrict__ Wkf, const f16* __restrict__ Wvf,
    const float* __restrict__ bq, const float* __restrict__ bk, const float* __restrict__ bv,
    f16* __restrict__ Qf_l, f16* __restrict__ Kf_l,
    f16* __restrict__ Qf_h, f16* __restrict__ Kf_h,
    f16* __restrict__ Qt_l, f16* __restrict__ Qt_h,
    f16* __restrict__ Vt_l, f16* __restrict__ Vt_h)
{
    int z = blockIdx.z, combo = z >> 5, b = z & 31, ww = combo % 3;
    const f16* In = ((combo < 3) ? lidT : hsiT) + (size_t)b*S_*C_;
    const f16* Wf = (ww==0) ? Wqf : (ww==1) ? Wkf : Wvf;
    const float* bias = (ww==0) ? bq : (ww==1) ? bk : bv;
    int s0 = blockIdx.x*64, o0 = blockIdx.y*64;
    int tid = threadIdx.x, w = tid>>6, lane = tid&63, quad = lane>>4, l15 = lane&15;

    __shared__ __align__(16) f16 sA[64*72];
    __shared__ __align__(16) f16 sB[64*72];

    f32x4 D[4];
    #pragma unroll
    for (int i = 0; i < 4; ++i) D[i] = (f32x4){0.f,0.f,0.f,0.f};

    int row = tid>>2, c16 = (tid&3)*16;
    for (int c0 = 0; c0 < 256; c0 += 64){
        __syncthreads();
        *(f16x8*)&sA[row*72 + c16]     = *(const f16x8*)(In + (size_t)(s0+row)*C_ + c0 + c16);
        *(f16x8*)&sA[row*72 + c16 + 8] = *(const f16x8*)(In + (size_t)(s0+row)*C_ + c0 + c16 + 8);
        *(f16x8*)&sB[row*72 + c16]     = *(const f16x8*)(Wf + (size_t)(o0+row)*C_ + c0 + c16);
        *(f16x8*)&sB[row*72 + c16 + 8] = *(const f16x8*)(Wf + (size_t)(o0+row)*C_ + c0 + c16 + 8);
        __syncthreads();
        #pragma unroll
        for (int sub = 0; sub < 2; ++sub){
            f16x8 a = *(const f16x8*)&sA[(w*16+l15)*72 + sub*32 + quad*8];
            #pragma unroll
            for (int bt = 0; bt < 4; ++bt){
                f16x8 bb = *(const f16x8*)&sB[(bt*16+l15)*72 + sub*32 + quad*8];
                D[bt] = __builtin_amdgcn_mfma_f32_16x16x32_f16(a, bb, D[bt], 0,0,0);
            }
        }
    }
    float bi[4];
    #pragma unroll
    for (int bt = 0; bt < 4; ++bt) bi[bt] = bias[o0 + bt*16 + l15];

    if (ww == 0){
        f16* F = ((combo==0) ? Qf_l : Qf_h) + (size_t)b*S_*C_;
        #pragma unroll
        for (int bt = 0; bt < 4; ++bt)
            #pragma unroll
            for (int r = 0; r < 4; ++r)
                F[(size_t)(s0 + w*16 + quad*4 + r)*C_ + o0 + bt*16 + l15] = (f16)(D[bt][r] + bi[bt]);
    } else if (ww == 1){
        f16* F = ((combo==1) ? Kf_l : Kf_h) + (size_t)b*S_*C_;
        #pragma unroll
        for (int bt = 0; bt < 4; ++bt)
            #pragma unroll
            for (int r = 0; r < 4; ++r)
                F[(size_t)(s0 + w*16 + quad*4 + r)*C_ + o0 + bt*16 + l15] = (f16)(D[bt][r] + bi[bt]);
    }
    if (ww != 1){
        __syncthreads();
        #pragma unroll
        for (int bt = 0; bt < 4; ++bt)
            #pragma unroll
            for (int r = 0; r < 4; ++r)
                sA[(bt*16+l15)*72 + w*16 + quad*4 + r] = (f16)(D[bt][r] + bi[bt]);
        __syncthreads();
        f16* T = (combo==0) ? Qt_l : (combo==3) ? Qt_h : (combo==2) ? Vt_l : Vt_h;
        T += (size_t)b*C_*S_;
        int o_r = tid>>2, s16b = (tid&3)*16;
        *(f16x8*)(T + (size_t)(o0+o_r)*S_ + s0 + s16b)     = *(const f16x8*)&sA[o_r*72 + s16b];
        *(f16x8*)(T + (size_t)(o0+o_r)*S_ + s0 + s16b + 8) = *(const f16x8*)&sA[o_r*72 + s16b + 8];
    }
}

// ---------------------------------------------------------------------------
// QVT1[c][s] = Qt_l*Vt_h ; QVT2[c][s] = Qt_h*Vt_l   (f16 elementwise)
// ---------------------------------------------------------------------------
__global__ __launch_bounds__(256) void k_qv(
    const f16* __restrict__ Qt_l, const f16* __restrict__ Qt_h,
    const f16* __restrict__ Vt_l, const f16* __restrict__ Vt_h,
    f16* __restrict__ QVT1, f16* __restrict__ QVT2)
{
    size_t idx = (size_t)(blockIdx.x*256 + threadIdx.x) * 8;
    f16x8 a = *(const f16x8*)(Qt_l+idx);
    f16x8 b = *(const f16x8*)(Vt_h+idx);
    *(f16x8*)(QVT1+idx) = a*b;
    f16x8 c = *(const f16x8*)(Qt_h+idx);
    f16x8 d = *(const f16x8*)(Vt_l+idx);
    *(f16x8*)(QVT2+idx) = c*d;
}

// ---------------------------------------------------------------------------
// MFMA flash attention — round-10 winner (146.3 us: round-2 schedule + T1
// XCD-contiguous remap, FETCH 278->49 MB) + lazy max-reduce:
//   The 16 shfl_xor/tile max-reduce moves INSIDE the rare rescale branch.
//   Trigger is bit-identical: row_max = max of per-lane partials, and
//   __any() ORs all 64 lanes, so any(partial>thr) == any(row_max>thr).
//   Non-trigger tiles (majority) now run ZERO cross-lane ops; P stays
//   bounded by e^8 (< f16 max) per the deferred-rescale invariant.
// Closed levers: split-phase staging (r1), dual q-row-group (r3, spill),
// t-tile 32 (r4), Qt*Vt fusion (r6, spill). Exec-bound: HBM 7%, 2 w/SIMD.
// ---------------------------------------------------------------------------
__global__ __launch_bounds__(256, 2) void k_attn(
    const f16* __restrict__ Qf_l, const f16* __restrict__ Kf_l,
    const f16* __restrict__ Qf_h, const f16* __restrict__ Kf_h,
    const f16* __restrict__ QVT1, const f16* __restrict__ QVT2,
    f16* __restrict__ cat)
{
    int lin  = blockIdx.y*16 + blockIdx.x;     // hw dispatch order (x fastest)
    int L    = (lin & 7)*128 + (lin >> 3);     // XCD-contiguous, bijective
    int inst = L >> 4;
    int s0   = (L & 15)*64;
    int b = inst >> 1, which = inst & 1;
    const f16* Qf  = (which ? Qf_h : Qf_l) + (size_t)b*S_*C_;
    const f16* Kf  = (which ? Kf_h : Kf_l) + (size_t)b*S_*C_;
    const f16* QVT = (which ? QVT2 : QVT1) + (size_t)b*C_*S_;
    f16* outp = cat + (size_t)b*S_*512 + (which ? 0 : 256);
    int tid = threadIdx.x, w = tid>>6, lane = tid&63, quad = lane>>4, l15 = lane&15;

    __shared__ __align__(16) f16 sK[64*264];    // [t][c] stride 264  (33792 B)
    __shared__ __align__(16) f16 sV[256*72];    // QVT [c][t64] stride 72 (36864 B)
    __shared__ __align__(16) f16 sPw[4][16*66]; // per-wave P scratch (8448 B)

    // Q A-frags in registers: wave w owns q-rows s0+16w .. s0+16w+15
    f16x8 qa[8];
    {
        const f16* qrow = Qf + (size_t)(s0 + w*16 + l15)*C_ + quad*8;
        #pragma unroll
        for (int i = 0; i < 8; ++i) qa[i] = *(const f16x8*)(qrow + i*32);
    }
    float mrun[4], lpart[4];
    #pragma unroll
    for (int r = 0; r < 4; ++r){ mrun[r] = -1e30f; lpart[r] = 0.f; }
    f32x4 pacc[16];
    #pragma unroll
    for (int i = 0; i < 16; ++i) pacc[i] = (f32x4){0.f,0.f,0.f,0.f};

    // prefetch registers for tile staging (T14 issue-early / write-late)
    f16x8 kreg[8], vreg[8];
    #pragma unroll
    for (int p = 0; p < 8; ++p){
        int idx = p*256 + tid;
        kreg[p] = *(const f16x8*)(Kf + (size_t)(idx>>5)*C_ + (idx&31)*8);
        vreg[p] = *(const f16x8*)(QVT + (size_t)(idx>>3)*S_ + (idx&7)*8);
    }

    for (int tt = 0; tt < 16; ++tt){
        __syncthreads();                  // prev tile's MFMA reads of sK/sV done
        #pragma unroll
        for (int p = 0; p < 8; ++p){      // write staged regs (waits vmcnt as needed)
            int idx = p*256 + tid;
            *(f16x8*)&sK[(idx>>5)*264 + (idx&31)*8] = kreg[p];
            *(f16x8*)&sV[(idx>>3)*72  + (idx&7)*8]  = vreg[p];
        }
        __syncthreads();

        // issue next tile's loads NOW; they complete under QK^T/softmax/PV
        if (tt < 15){
            int t0n = (tt+1)*64;
            #pragma unroll
            for (int p = 0; p < 8; ++p){
                int idx = p*256 + tid;
                kreg[p] = *(const f16x8*)(Kf + (size_t)(t0n + (idx>>5))*C_ + (idx&31)*8);
                vreg[p] = *(const f16x8*)(QVT + (size_t)(idx>>3)*S_ + t0n + (idx&7)*8);
            }
        }

        // ---- scores: D[16 s][64 t] per wave ----
        f32x4 sacc[4];
        #pragma unroll
        for (int bt = 0; bt < 4; ++bt) sacc[bt] = (f32x4){0.f,0.f,0.f,0.f};
        __builtin_amdgcn_s_setprio(1);
        #pragma unroll
        for (int ks = 0; ks < 8; ++ks){
            #pragma unroll
            for (int bt = 0; bt < 4; ++bt){
                f16x8 kb = *(const f16x8*)&sK[(bt*16+l15)*264 + ks*32 + quad*8];
                sacc[bt] = __builtin_amdgcn_mfma_f32_16x16x32_f16(qa[ks], kb, sacc[bt], 0,0,0);
            }
        }
        __builtin_amdgcn_s_setprio(0);

        // ---- online softmax: lazy max-reduce + deferred rescale ----
        float pmax[4];                         // per-lane partial row max
        #pragma unroll
        for (int r = 0; r < 4; ++r)
            pmax[r] = fmaxf(fmaxf(sacc[0][r], sacc[1][r]), fmaxf(sacc[2][r], sacc[3][r]));
        bool need = (pmax[0] > mrun[0]+8.f) | (pmax[1] > mrun[1]+8.f) |
                    (pmax[2] > mrun[2]+8.f) | (pmax[3] > mrun[3]+8.f);
        if (__any(need)){                      // rare: full reduce + rescale
            #pragma unroll
            for (int r = 0; r < 4; ++r){
                float t = pmax[r];
                #pragma unroll
                for (int off = 1; off < 16; off <<= 1) t = fmaxf(t, __shfl_xor(t, off, 64));
                float mn = fmaxf(mrun[r], t);
                float al = __expf(mrun[r] - mn);
                mrun[r] = mn;
                lpart[r] *= al;
                #pragma unroll
                for (int cf = 0; cf < 16; ++cf) pacc[cf][r] *= al;
            }
        }
        #pragma unroll
        for (int r = 0; r < 4; ++r){
            float local = 0.f;
            #pragma unroll
            for (int bt = 0; bt < 4; ++bt){
                float p = __expf(sacc[bt][r] - mrun[r]);
                sPw[w][(quad*4+r)*66 + bt*16 + l15] = (f16)p;
                local += p;
            }
            lpart[r] += local;
        }
        // P A-frags (wave-internal LDS round-trip; no barrier)
        f16x8 pa0 = *(const f16x8*)&sPw[w][l15*66 + quad*8];
        f16x8 pa1 = *(const f16x8*)&sPw[w][l15*66 + 32 + quad*8];

        // ---- PV: D[16 s][256 c] per wave ----
        __builtin_amdgcn_s_setprio(1);
        #pragma unroll
        for (int cf = 0; cf < 16; ++cf){
            f16x8 vb0 = *(const f16x8*)&sV[(cf*16+l15)*72 + quad*8];
            f16x8 vb1 = *(const f16x8*)&sV[(cf*16+l15)*72 + 32 + quad*8];
            pacc[cf] = __builtin_amdgcn_mfma_f32_16x16x32_f16(pa0, vb0, pacc[cf], 0,0,0);
            pacc[cf] = __builtin_amdgcn_mfma_f32_16x16x32_f16(pa1, vb1, pacc[cf], 0,0,0);
        }
        __builtin_amdgcn_s_setprio(0);
    }

    // ---- epilogue: deferred l reduction + normalize ----
    #pragma unroll
    for (int r = 0; r < 4; ++r){
        #pragma unroll
        for (int off = 1; off < 16; off <<= 1) lpart[r] += __shfl_xor(lpart[r], off, 64);
    }
    #pragma unroll
    for (int r = 0; r < 4; ++r){
        int s = w*16 + quad*4 + r;
        float rl = 1.f / lpart[r];
        #pragma unroll
        for (int cf = 0; cf < 16; ++cf)
            outp[(size_t)(s0+s)*512 + cf*16 + l15] = (f16)(pacc[cf][r] * rl);
    }
}

// ---------------------------------------------------------------------------
// 1x1 conv + bias + residual, f16 MFMA
// ---------------------------------------------------------------------------
__global__ __launch_bounds__(256) void k_conv(
    const f16* __restrict__ cat, const f16* __restrict__ cwf,
    const float* __restrict__ cb, const float* __restrict__ x,
    float* __restrict__ out)
{
    int b = blockIdx.z;
    int s0 = blockIdx.x*64, o0 = blockIdx.y*64;
    int tid = threadIdx.x, w = tid>>6, lane = tid&63, quad = lane>>4, l15 = lane&15;

    __shared__ __align__(16) f16 sA[64*72];
    __shared__ __align__(16) f16 sB[64*72];

    f32x4 D[4];
    #pragma unroll
    for (int i = 0; i < 4; ++i) D[i] = (f32x4){0.f,0.f,0.f,0.f};

    const f16* catb = cat + (size_t)b*S_*512;
    int row = tid>>2, c16 = (tid&3)*16;
    for (int i0 = 0; i0 < 512; i0 += 64){
        __syncthreads();
        *(f16x8*)&sA[row*72 + c16]     = *(const f16x8*)(cwf + (size_t)(o0+row)*512 + i0 + c16);
        *(f16x8*)&sA[row*72 + c16 + 8] = *(const f16x8*)(cwf + (size_t)(o0+row)*512 + i0 + c16 + 8);
        *(f16x8*)&sB[row*72 + c16]     = *(const f16x8*)(catb + (size_t)(s0+row)*512 + i0 + c16);
        *(f16x8*)&sB[row*72 + c16 + 8] = *(const f16x8*)(catb + (size_t)(s0+row)*512 + i0 + c16 + 8);
        __syncthreads();
        #pragma unroll
        for (int sub = 0; sub < 2; ++sub){
            f16x8 a = *(const f16x8*)&sA[(w*16+l15)*72 + sub*32 + quad*8];
            #pragma unroll
            for (int bt = 0; bt < 4; ++bt){
                f16x8 bb = *(const f16x8*)&sB[(bt*16+l15)*72 + sub*32 + quad*8];
                D[bt] = __builtin_amdgcn_mfma_f32_16x16x32_f16(a, bb, D[bt], 0,0,0);
            }
        }
    }
    #pragma unroll
    for (int r = 0; r < 4; ++r){
        int o_loc = w*16 + quad*4 + r;
        float cbv = cb[o0 + o_loc];
        size_t base = (size_t)b*C_*S_ + (size_t)(o0+o_loc)*S_ + s0;
        #pragma unroll
        for (int bt = 0; bt < 4; ++bt){
            size_t a = base + bt*16 + l15;
            out[a] = D[bt][r] + cbv + x[a];
        }
    }
}

// ---------------------------------------------------------------------------
extern "C" void kernel_launch(void* const* d_in, const int* in_sizes, int n_in,
                              void* d_out, int out_size, void* d_ws, size_t ws_size,
                              hipStream_t stream)
{
    const float* lidar = (const float*)d_in[0];
    const float* hsi   = (const float*)d_in[1];
    const float* x     = (const float*)d_in[2];
    const float* Wq = (const float*)d_in[3];  const float* bq = (const float*)d_in[4];
    const float* Wk = (const float*)d_in[5];  const float* bk = (const float*)d_in[6];
    const float* Wv = (const float*)d_in[7];  const float* bv = (const float*)d_in[8];
    const float* cw = (const float*)d_in[9];  const float* cb = (const float*)d_in[10];
    const float* rw1 = (const float*)d_in[11]; const float* rb1 = (const float*)d_in[12];
    const float* rw2 = (const float*)d_in[13]; const float* rb2 = (const float*)d_in[14];
    float* outF = (float*)d_out;
    char* ws = (char*)d_ws;
    const size_t M = 1ull<<20;

    f16* lidT = (f16*)(ws +   0*M);   // alias: QVT1 after k_qkv
    f16* hsiT = (f16*)(ws +  16*M);   // alias: QVT2 after k_qkv
    f16* Qf_l = (f16*)(ws +  32*M);
    f16* Kf_l = (f16*)(ws +  48*M);
    f16* Qf_h = (f16*)(ws +  64*M);
    f16* Kf_h = (f16*)(ws +  80*M);
    f16* Qt_l = (f16*)(ws +  96*M);
    f16* Qt_h = (f16*)(ws + 112*M);
    f16* cat  = (f16*)(ws + 128*M);   // 32 MiB
    float* g  = (float*)(ws + 160*M); // 16 KB raw channel sums
    f16* Wqf  = (f16*)(ws + 161*M);
    f16* Wkf  = (f16*)(ws + 161*M + 131072);
    f16* Wvf  = (f16*)(ws + 161*M + 262144);
    f16* cwf  = (f16*)(ws + 161*M + 393216);
    f16* QVT1 = lidT;
    f16* QVT2 = hsiT;
    f16* Vt_l = (f16*)d_out;            // dead until k_conv; disjoint from path_prob
    f16* Vt_h = (f16*)d_out + 8388608;

    hipMemsetAsync(g, 0, 4096*sizeof(float), stream);
    k_cvtw<<<320, 256, 0, stream>>>(Wq, Wk, Wv, cw, Wqf, Wkf, Wvf, cwf);
    k_cvt<<<dim3(16,4,64), 256, 0, stream>>>(lidar, hsi, lidT, hsiT, g);
    k_mlp<<<32, 256, 0, stream>>>(g, rw1, rb1, rw2, rb2, outF);
    k_qkv<<<dim3(16,4,192), 256, 0, stream>>>(lidT, hsiT, Wqf, Wkf, Wvf, bq, bk, bv,
                                              Qf_l, Kf_l, Qf_h, Kf_h, Qt_l, Qt_h, Vt_l, Vt_h);
    k_qv<<<4096, 256, 0, stream>>>(Qt_l, Qt_h, Vt_l, Vt_h, QVT1, QVT2);
    k_attn<<<dim3(16,64), 256, 0, stream>>>(Qf_l, Kf_l, Qf_h, Kf_h, QVT1, QVT2, cat);
    k_conv<<<dim3(16,4,32), 256, 0, stream>>>(cat, cwf, cb, x, outF);
}